// Round 8
// baseline (530.781 us; speedup 1.0000x reference)
//
#include <hip/hip_runtime.h>
#include <hip/hip_bf16.h>
#include <stdint.h>

// BidirectionalAttention2: two flash-attention passes over sim = v1 @ v2^T.
// R8: 3-pass QK restored (R7's 2-pass failed absmax 0.144 > 0.104).
//     New 80KB split-buffer pipeline to keep 2 blocks/CU:
//       kh+vt double-buffered (2x32KB) + kl SINGLE-buffered (16KB) = 80KB,
//       2 blocks x 80KB = 160KiB exactly. sh_it aliased into kls.
//     Per kt: issue kl(kt)+khvt(kt+1); QK-hi (32 MFMA, khA); vmcnt(4)+barrier;
//     QK-lo (16 MFMA, kls); softmax; PV (vtA); vmcnt(0)+barrier; swap.
//     kl latency hides under QK-hi; khvt latency hides under the whole body.
//     Kept: exact masked-key lump, compacted K/V, per-XCD work steal, setprio.

#define MASK_FILL -1e-07f

typedef unsigned short u16;
typedef __attribute__((ext_vector_type(8))) short short8;
typedef __attribute__((ext_vector_type(4))) float f32x4;
typedef __attribute__((ext_vector_type(4))) u16 u16x4;

#define NB 64
#define LL 1024
#define DD 256
#define BQ 128
#define BK 32
#define ELEMS ((size_t)NB * LL * DD)
#define NIT_STREAM 128   // items per stream: qt(8) x dir(2) x boct(8)

__device__ __forceinline__ unsigned bf16_rne(float f) {
    unsigned u = __float_as_uint(f);
    return (u + 0x7fffu + ((u >> 16) & 1u)) >> 16;
}

__device__ __forceinline__ void gll16(const u16* g, u16* l) {
    __builtin_amdgcn_global_load_lds(
        (const __attribute__((address_space(1))) void*)g,
        (__attribute__((address_space(3))) void*)l, 16, 0, 0);
}

// ---- mask dtype detection + normalization ----------------------------------
__global__ __launch_bounds__(256) void mask_detect(
    const unsigned* __restrict__ m1, const unsigned* __restrict__ m2,
    int* __restrict__ flag)
{
    unsigned acc = 0;
    for (int i = threadIdx.x; i < 4096; i += 256)
        acc |= (m1[i] | m2[i]) & ~1u;
    __shared__ unsigned red[256];
    red[threadIdx.x] = acc;
    __syncthreads();
    for (int o = 128; o; o >>= 1) {
        if (threadIdx.x < o) red[threadIdx.x] |= red[threadIdx.x + o];
        __syncthreads();
    }
    if (threadIdx.x == 0) *flag = red[0] ? 1 : 0;
}

__global__ __launch_bounds__(256) void mask_convert(
    const void* __restrict__ m, const int* __restrict__ flag,
    int* __restrict__ outm)
{
    int i = blockIdx.x * 256 + threadIdx.x;
    int v;
    if (*flag) v = ((const unsigned char*)m)[i];
    else       v = ((const int*)m)[i];
    outm[i] = v ? 1 : 0;
}

// ---- zero only the masked output rows ---------------------------------------
__global__ __launch_bounds__(256) void zero_rows(
    const int* __restrict__ cm1, const int* __restrict__ cm2,
    float* __restrict__ out)
{
    int r = blockIdx.x * 8 + (threadIdx.x >> 5);
    int c = (threadIdx.x & 31) * 8;
    int m = (r < NB * LL) ? cm1[r] : cm2[r - NB * LL];
    if (m) {
        f32x4 z4 = {0.f, 0.f, 0.f, 0.f};
        *(f32x4*)(out + (size_t)r * DD + c) = z4;
        *(f32x4*)(out + (size_t)r * DD + c + 4) = z4;
    }
}

// ---- per-batch compaction: qidx (ordered unmasked rows), posAll, qcnt -------
__global__ __launch_bounds__(256) void build_qidx(
    const int* __restrict__ mask, int* __restrict__ qidx,
    int* __restrict__ posAll, int* __restrict__ qcnt)
{
    int b = blockIdx.x, tid = threadIdx.x;
    __shared__ int ps[256];
    const int* mb = mask + b * LL;
    int f[4], s = 0;
#pragma unroll
    for (int j = 0; j < 4; ++j) { f[j] = (mb[tid * 4 + j] == 0) ? 1 : 0; s += f[j]; }
    ps[tid] = s;
    __syncthreads();
    for (int off = 1; off < 256; off <<= 1) {
        int v = (tid >= off) ? ps[tid - off] : 0;
        __syncthreads();
        ps[tid] += v;
        __syncthreads();
    }
    int pos = (tid > 0) ? ps[tid - 1] : 0;
#pragma unroll
    for (int j = 0; j < 4; ++j) {
        posAll[b * LL + tid * 4 + j] = pos;
        if (f[j]) qidx[b * LL + (pos++)] = tid * 4 + j;
    }
    if (tid == 255) qcnt[b] = ps[255];
}

// ---- prep: fp32 -> (hi,lo) bf16 COMPACTED rows + compacted transpose + ------
// ---- deterministic per-tile masked-V partial sums ---------------------------
__global__ __launch_bounds__(256) void prep2_kernel(
    const float* __restrict__ x1, u16* __restrict__ h1, u16* __restrict__ l1,
    u16* __restrict__ t1, const int* __restrict__ cm1,
    const int* __restrict__ pa1, const int* __restrict__ qi1,
    const int* __restrict__ qc1,
    const float* __restrict__ x2, u16* __restrict__ h2, u16* __restrict__ l2,
    u16* __restrict__ t2, const int* __restrict__ cm2,
    const int* __restrict__ pa2, const int* __restrict__ qi2,
    const int* __restrict__ qc2,
    float* __restrict__ part)   // [2][NB][16][256]
{
    __shared__ u16 t[64][65];
    __shared__ float ps2[16][68];
    int blk = blockIdx.x;
    int tensor = blk >> 12;
    blk &= 4095;
    const float* x = tensor ? x2 : x1;
    u16* h  = tensor ? h2 : h1;
    u16* lo = tensor ? l2 : l1;
    u16* xt = tensor ? t2 : t1;
    const int* cm = tensor ? cm2 : cm1;
    const int* pa = tensor ? pa2 : pa1;
    const int* qi = tensor ? qi2 : qi1;
    const int* qc = tensor ? qc2 : qc1;
    int b = blk >> 6, lt = (blk >> 2) & 15, dt = blk & 3;
    int l0 = lt * 64, d0 = dt * 64;
    int tid = threadIdx.x;
    int sub = tid >> 4;
    int c16 = tid & 15;
    float vpart[4] = {0.f, 0.f, 0.f, 0.f};
#pragma unroll
    for (int p = 0; p < 4; ++p) {
        int row = p * 16 + sub;
        int l = l0 + row;
        int masked = cm[b * LL + l];
        int slot = pa[b * LL + l];
        f32x4 v = *(const f32x4*)(x + ((size_t)b * LL + l) * DD + d0 + c16 * 4);
        u16x4 hv, lv;
#pragma unroll
        for (int e = 0; e < 4; ++e) {
            unsigned hb = bf16_rne(v[e]);
            float hf = __uint_as_float(hb << 16);
            unsigned lb = bf16_rne(v[e] - hf);
            hv[e] = (u16)hb;
            lv[e] = (u16)lb;
            t[c16 * 4 + e][row] = (u16)hb;
            if (masked) vpart[e] += v[e];
        }
        if (!masked) {
            size_t gi = ((size_t)b * LL + slot) * DD + d0 + c16 * 4;
            *(u16x4*)(h + gi) = hv;
            *(u16x4*)(lo + gi) = lv;
        }
    }
#pragma unroll
    for (int e = 0; e < 4; ++e) ps2[sub][c16 * 4 + e] = vpart[e];
    __syncthreads();
    int pos_base = pa[b * LL + l0];
    int cntb = qc[b];
    int nun = ((lt == 15) ? cntb : pa[b * LL + l0 + 64]) - pos_base;
#pragma unroll
    for (int p = 0; p < 4; ++p) {
        int d = p * 16 + sub;
#pragma unroll
        for (int e = 0; e < 4; ++e) {
            int j = c16 * 4 + e;
            if (j < nun) {
                int col = qi[b * LL + pos_base + j] - l0;
                xt[((size_t)b * DD + d0 + d) * LL + pos_base + j] = t[d][col];
            }
        }
    }
    if (tid < 64) {
        float s = 0.f;
#pragma unroll
        for (int k = 0; k < 16; ++k) s += ps2[k][tid];
        part[(((size_t)tensor * NB + b) * 16 + lt) * 256 + d0 + tid] = s;
    }
}

// ---- reduce per-tile partials -> Vsum[tensor][b][256] (fixed order) ---------
__global__ __launch_bounds__(256) void vsum_reduce(
    const float* __restrict__ part, float* __restrict__ vsum)
{
    int blk = blockIdx.x;       // tensor*NB + b
    int d = threadIdx.x;
    float s = 0.f;
#pragma unroll
    for (int lt = 0; lt < 16; ++lt)
        s += part[((size_t)blk * 16 + lt) * 256 + d];
    vsum[(size_t)blk * DD + d] = s;
}

// ---- persistent fused flash: 3-pass QK, 80KB split-buffer, 2 blocks/CU ------
// 512 blocks x 512 thr. stream = blockIdx&7 -> batches b%8 (XCD L2 locality).
__global__ __launch_bounds__(512, 4) void flash_fused(
    const u16* __restrict__ v1h, const u16* __restrict__ v1l,
    const u16* __restrict__ v2h, const u16* __restrict__ v2l,
    const u16* __restrict__ v1t, const u16* __restrict__ v2t,
    const int* __restrict__ qidx1, const int* __restrict__ qcnt1,
    const int* __restrict__ qidx2, const int* __restrict__ qcnt2,
    const float* __restrict__ vsum, int* __restrict__ ctr,
    float* __restrict__ out)
{
    int strm0 = blockIdx.x & 7;
    int tid = threadIdx.x;
    int w = tid >> 6, lane = tid & 63;
    int lq = lane & 15, g = lane >> 4;

    // 80KB total: kh 2x16KB + vt 2x16KB + kl 1x16KB. sh_it aliased into kls.
    __shared__ __align__(16) u16 kh2[2][BK * DD];  // [key][d], chunk ^ (key&7)
    __shared__ __align__(16) u16 vt2[2][BK * DD];  // [d][key], chunk ^ (d&3)^((d>>2)&3)
    __shared__ __align__(16) u16 kls[BK * DD];     // kl single buffer

    const int pvcc = (g ^ (lq & 3) ^ ((lq >> 2) & 3)) * 8;

    // kh/vt: 32 x 1KB units, 4/wave. kl: 16 x 1KB units, 2/wave.
#define STAGE_KHVT(PKH, PVT, KT, KVB, VTB, KHG, VTG)                            \
    {                                                                           \
        int k0s = (KT) * BK;                                                    \
        _Pragma("unroll")                                                       \
        for (int t = 0; t < 4; ++t) {                                           \
            int u = t * 8 + w;                                                  \
            int n = u & 15;                                                     \
            if (u < 16) {                                                       \
                unsigned phys = (unsigned)n * 1024u + (unsigned)lane * 16u;     \
                unsigned key = phys >> 9;                                       \
                unsigned cl = ((phys >> 4) & 31u) ^ (key & 7u);                 \
                size_t koff = (KVB) + (size_t)(k0s + (int)key) * DD + cl * 8;   \
                gll16((KHG) + koff, (PKH) + n * 512);                           \
            } else {                                                            \
                unsigned dv = (unsigned)n * 16u + ((unsigned)lane >> 2);        \
                unsigned cv = ((unsigned)lane & 3u) ^ (dv & 3u) ^ ((dv >> 2) & 3u); \
                size_t voff = (VTB) + (size_t)dv * LL + (unsigned)k0s + cv * 8; \
                gll16((VTG) + voff, (PVT) + n * 512);                           \
            }                                                                   \
        }                                                                       \
    }
#define STAGE_KL(KT, KVB, KLG)                                                  \
    {                                                                           \
        int k0s = (KT) * BK;                                                    \
        _Pragma("unroll")                                                       \
        for (int t = 0; t < 2; ++t) {                                           \
            int n = t * 8 + w;                                                  \
            unsigned phys = (unsigned)n * 1024u + (unsigned)lane * 16u;         \
            unsigned key = phys >> 9;                                           \
            unsigned cl = ((phys >> 4) & 31u) ^ (key & 7u);                     \
            size_t koff = (KVB) + (size_t)(k0s + (int)key) * DD + cl * 8;       \
            gll16((KLG) + koff, kls + n * 512);                                 \
        }                                                                       \
    }

    for (int ss = 0; ss < 8; ++ss) {
        int s2 = (strm0 + ss) & 7;
        for (;;) {
            __syncthreads();                       // prev item's kls/LDS reads done
            if (tid == 0) *(int*)kls = atomicAdd(&ctr[s2], 1);
            __syncthreads();
            int it = *(const int*)kls;
            __syncthreads();                       // all read sh_it before kls overwrite
            if (it >= NIT_STREAM) break;
            int qt  = it & 7;
            int dir = (it >> 3) & 1;
            int b   = ((it >> 4) << 3) + s2;

            const u16 *qh_g, *ql_g, *kh_g, *kl_g, *vt_g;
            const int *qidx, *qcq, *qck;
            const float* vsp;
            float* ob;
            if (dir == 0) { qh_g=v1h; ql_g=v1l; kh_g=v2h; kl_g=v2l; vt_g=v2t;
                            qidx=qidx1; qcq=qcnt1; qck=qcnt2;
                            vsp = vsum + ((size_t)NB + b) * DD; ob = out; }
            else          { qh_g=v2h; ql_g=v2l; kh_g=v1h; kl_g=v1l; vt_g=v1t;
                            qidx=qidx2; qcq=qcnt2; qck=qcnt1;
                            vsp = vsum + (size_t)b * DD; ob = out + ELEMS; }
            int cnt_q = qcq[b];
            if (qt * BQ >= cnt_q) continue;
            int cnt_k = qck[b];
            int nkt = (cnt_k + BK - 1) >> 5;

            int qslot = qt * BQ + w * 16 + lq;
            bool qvalid = qslot < cnt_q;

            // Q fragments from compacted rows (row == qslot)
            const u16* qbh = qh_g + ((size_t)b * LL + qslot) * DD + g * 8;
            const u16* qbl = ql_g + ((size_t)b * LL + qslot) * DD + g * 8;
            short8 qhf[8], qlf[8];
#pragma unroll
            for (int ks = 0; ks < 8; ++ks) {
                qhf[ks] = *(const short8*)(qbh + ks * 32);
                qlf[ks] = *(const short8*)(qbl + ks * 32);
            }

            float m = MASK_FILL, z = 0.f;
            f32x4 o[16];
#pragma unroll
            for (int i2 = 0; i2 < 16; ++i2) o[i2] = (f32x4){0.f, 0.f, 0.f, 0.f};

            const size_t kv_base = (size_t)b * LL * DD;
            const size_t vt_base = (size_t)b * DD * LL;

            if (nkt > 0) {
                u16 *khA = kh2[0], *khB = kh2[1];
                u16 *vtA = vt2[0], *vtB = vt2[1];

                STAGE_KHVT(khA, vtA, 0, kv_base, vt_base, kh_g, vt_g);
                asm volatile("s_waitcnt vmcnt(0)" ::: "memory");
                __builtin_amdgcn_s_barrier();
                __builtin_amdgcn_sched_barrier(0);

                for (int kt = 0; kt < nkt; ++kt) {
                    int k0 = kt * BK;
                    STAGE_KL(kt, kv_base, kl_g);                 // 2 gll (oldest)
                    if (kt + 1 < nkt)
                        STAGE_KHVT(khB, vtB, kt + 1, kv_base, vt_base, kh_g, vt_g);

                    // QK hi: S^T += Kh @ (Qh + Ql), on khA
                    f32x4 sa0 = (f32x4){0.f, 0.f, 0.f, 0.f};
                    f32x4 sa1 = (f32x4){0.f, 0.f, 0.f, 0.f};
                    __builtin_amdgcn_s_setprio(1);
#pragma unroll
                    for (int ks = 0; ks < 8; ++ks) {
                        int cidx = ((ks * 4 + g) ^ (lq & 7)) * 8;
                        short8 kh0 = *(const short8*)&khA[lq * 256 + cidx];
                        short8 kh1 = *(const short8*)&khA[(16 + lq) * 256 + cidx];
                        sa0 = __builtin_amdgcn_mfma_f32_16x16x32_bf16(kh0, qhf[ks], sa0, 0, 0, 0);
                        sa0 = __builtin_amdgcn_mfma_f32_16x16x32_bf16(kh0, qlf[ks], sa0, 0, 0, 0);
                        sa1 = __builtin_amdgcn_mfma_f32_16x16x32_bf16(kh1, qhf[ks], sa1, 0, 0, 0);
                        sa1 = __builtin_amdgcn_mfma_f32_16x16x32_bf16(kh1, qlf[ks], sa1, 0, 0, 0);
                    }
                    __builtin_amdgcn_s_setprio(0);

                    // kl landed (its 2 loads are oldest; 4 khvt may remain)
                    if (kt + 1 < nkt) {
                        asm volatile("s_waitcnt vmcnt(4)" ::: "memory");
                    } else {
                        asm volatile("s_waitcnt vmcnt(0)" ::: "memory");
                    }
                    __builtin_amdgcn_s_barrier();
                    __builtin_amdgcn_sched_barrier(0);

                    // QK lo: S^T += Kl @ Qh, on kls
                    __builtin_amdgcn_s_setprio(1);
#pragma unroll
                    for (int ks = 0; ks < 8; ++ks) {
                        int cidx = ((ks * 4 + g) ^ (lq & 7)) * 8;
                        short8 kl0 = *(const short8*)&kls[lq * 256 + cidx];
                        short8 kl1 = *(const short8*)&kls[(16 + lq) * 256 + cidx];
                        sa0 = __builtin_amdgcn_mfma_f32_16x16x32_bf16(kl0, qhf[ks], sa0, 0, 0, 0);
                        sa1 = __builtin_amdgcn_mfma_f32_16x16x32_bf16(kl1, qhf[ks], sa1, 0, 0, 0);
                    }
                    __builtin_amdgcn_s_setprio(0);

                    float s[8];
#pragma unroll
                    for (int i2 = 0; i2 < 4; ++i2) { s[i2] = sa0[i2]; s[4 + i2] = sa1[i2]; }
                    if (kt == nkt - 1) {             // tail clamp: fake keys -> -inf
                        int base = k0 + 4 * g;
#pragma unroll
                        for (int i2 = 0; i2 < 4; ++i2) {
                            if (base + i2 >= cnt_k)      s[i2]     = -1e30f;
                            if (base + 16 + i2 >= cnt_k) s[4 + i2] = -1e30f;
                        }
                    }
                    float pmax = s[0];
#pragma unroll
                    for (int i2 = 1; i2 < 8; ++i2) pmax = fmaxf(pmax, s[i2]);
                    pmax = fmaxf(pmax, __shfl_xor(pmax, 16));
                    pmax = fmaxf(pmax, __shfl_xor(pmax, 32));
                    if (__any(pmax > m)) {
                        float mnew = fmaxf(m, pmax);
                        float alpha = __expf(m - mnew);
                        z *= alpha;
#pragma unroll
                        for (int i2 = 0; i2 < 16; ++i2) o[i2] *= alpha;
                        m = mnew;
                    }
                    float p[8], ps = 0.f;
#pragma unroll
                    for (int i2 = 0; i2 < 8; ++i2) { p[i2] = __expf(s[i2] - m); ps += p[i2]; }
                    ps += __shfl_xor(ps, 16);
                    ps += __shfl_xor(ps, 32);
                    z += ps;

                    unsigned pk00 = bf16_rne(p[0]) | (bf16_rne(p[1]) << 16);
                    unsigned pk01 = bf16_rne(p[2]) | (bf16_rne(p[3]) << 16);
                    unsigned pk10 = bf16_rne(p[4]) | (bf16_rne(p[5]) << 16);
                    unsigned pk11 = bf16_rne(p[6]) | (bf16_rne(p[7]) << 16);
                    int srcA = ((lane & 16) << 1) | lq;
                    int srcB = srcA + 16;
                    unsigned a00 = (unsigned)__shfl((int)pk00, srcA);
                    unsigned a01 = (unsigned)__shfl((int)pk01, srcA);
                    unsigned a10 = (unsigned)__shfl((int)pk10, srcA);
                    unsigned a11 = (unsigned)__shfl((int)pk11, srcA);
                    unsigned b00 = (unsigned)__shfl((int)pk00, srcB);
                    unsigned b01 = (unsigned)__shfl((int)pk01, srcB);
                    unsigned b10 = (unsigned)__shfl((int)pk10, srcB);
                    unsigned b11 = (unsigned)__shfl((int)pk11, srcB);
                    bool sel = (g >> 1) != 0;
                    union { unsigned u[4]; short8 v; } pf;
                    pf.u[0] = sel ? a10 : a00;
                    pf.u[1] = sel ? a11 : a01;
                    pf.u[2] = sel ? b10 : b00;
                    pf.u[3] = sel ? b11 : b01;

                    __builtin_amdgcn_s_setprio(1);
#pragma unroll
                    for (int dt = 0; dt < 16; ++dt) {
                        int d = dt * 16 + lq;
                        short8 vf = *(const short8*)&vtA[d * 32 + pvcc];
                        o[dt] = __builtin_amdgcn_mfma_f32_16x16x32_bf16(vf, pf.v, o[dt], 0, 0, 0);
                    }
                    __builtin_amdgcn_s_setprio(0);

                    if (kt + 1 < nkt) {
                        // khvt(kt+1) issued a full body ago -> near-free drain
                        asm volatile("s_waitcnt vmcnt(0)" ::: "memory");
                        __builtin_amdgcn_s_barrier();
                        __builtin_amdgcn_sched_barrier(0);
                    }
                    u16* tp;
                    tp = khA; khA = khB; khB = tp;
                    tp = vtA; vtA = vtB; vtB = tp;
                }
            }

            // exact masked-key lump: all masked logits == MASK_FILL
            float wl = __expf(MASK_FILL - m);      // m >= MASK_FILL always
            z += (float)(LL - cnt_k) * wl;
#pragma unroll
            for (int dt = 0; dt < 16; ++dt) {
                f32x4 vv = *(const f32x4*)(vsp + dt * 16 + 4 * g);
                o[dt] += wl * vv;
            }

            if (qvalid) {
                int qrow = qidx[b * LL + qslot];
                float zinv = 1.0f / z;
                float* orow = ob + ((size_t)b * LL + qrow) * DD + 4 * g;
#pragma unroll
                for (int dt = 0; dt < 16; ++dt) {
                    f32x4 vv = o[dt] * zinv;
                    *(f32x4*)(orow + dt * 16) = vv;
                }
            }
        }
    }
#undef STAGE_KHVT
#undef STAGE_KL
}

extern "C" void kernel_launch(void* const* d_in, const int* in_sizes, int n_in,
                              void* d_out, int out_size, void* d_ws, size_t ws_size,
                              hipStream_t stream)
{
    const float* v1      = (const float*)d_in[0];
    const void*  v1_mask = d_in[1];
    const float* v2      = (const float*)d_in[2];
    const void*  v2_mask = d_in[3];
    float* out = (float*)d_out;

    u16* v1h = (u16*)d_ws;           // compacted hi (row = compact slot)
    u16* v1l = v1h + ELEMS;
    u16* v2h = v1l + ELEMS;
    u16* v2l = v2h + ELEMS;
    u16* v1t = v2l + ELEMS;          // compacted transpose [b][d][slot]
    u16* v2t = v1t + ELEMS;
    int* qidx1 = (int*)(v2t + ELEMS);
    int* qcnt1 = qidx1 + NB * LL;
    int* qidx2 = qcnt1 + NB;
    int* qcnt2 = qidx2 + NB * LL;
    int* cm1   = qcnt2 + NB;
    int* cm2   = cm1 + NB * LL;
    int* pa1   = cm2 + NB * LL;
    int* pa2   = pa1 + NB * LL;
    int* mflag = pa2 + NB * LL;
    float* part = (float*)(mflag + 16);          // [2][NB][16][256]
    float* vsum = part + 2 * NB * 16 * 256;      // [2][NB][256]
    int* ctr    = (int*)(vsum + 2 * NB * 256);   // [8] steal counters

    hipMemsetAsync(ctr, 0, 8 * sizeof(int), stream);

    mask_detect<<<dim3(1), dim3(256), 0, stream>>>(
        (const unsigned*)v1_mask, (const unsigned*)v2_mask, mflag);
    mask_convert<<<dim3(NB * LL / 256), dim3(256), 0, stream>>>(v1_mask, mflag, cm1);
    mask_convert<<<dim3(NB * LL / 256), dim3(256), 0, stream>>>(v2_mask, mflag, cm2);

    zero_rows<<<dim3(2 * NB * LL / 8), dim3(256), 0, stream>>>(cm1, cm2, out);
    build_qidx<<<dim3(NB), dim3(256), 0, stream>>>(cm1, qidx1, pa1, qcnt1);
    build_qidx<<<dim3(NB), dim3(256), 0, stream>>>(cm2, qidx2, pa2, qcnt2);

    prep2_kernel<<<dim3(2 * NB * 64), dim3(256), 0, stream>>>(
        v1, v1h, v1l, v1t, cm1, pa1, qidx1, qcnt1,
        v2, v2h, v2l, v2t, cm2, pa2, qidx2, qcnt2, part);
    vsum_reduce<<<dim3(2 * NB), dim3(256), 0, stream>>>(part, vsum);

    // persistent, work-stealing fused flash (2 blocks per CU, 80KB LDS each)
    flash_fused<<<dim3(512), dim3(512), 0, stream>>>(
        v1h, v1l, v2h, v2l, v1t, v2t,
        qidx1, qcnt1, qidx2, qcnt2, vsum, ctr, out);
}

// Round 9
// 302.959 us; speedup vs baseline: 1.7520x; 1.7520x over previous
//
#include <hip/hip_runtime.h>
#include <hip/hip_bf16.h>
#include <stdint.h>

// BidirectionalAttention2: two flash-attention passes over sim = v1 @ v2^T.
// R9: R8's 80KB split-buffer pipeline with the REGISTER CAP RELEASED.
//     R8's defect: __launch_bounds__(512,4) capped unified VGPR/AGPR at 128
//     -> compiler allocated 64 arch VGPRs and SPILLED o[16] to scratch
//     (FETCH 80->640MB, flash 167->437us). Fix: __launch_bounds__(512,2)
//     (cap 256); natural allocation ~116 still gives 4 waves/SIMD -> the
//     same 2 blocks/CU, now spill-free. LDS 2x80KB = 160KB exactly.
//     Kept: 3-pass QK, kh/vt dbuf + kl single buffer, counted vmcnt,
//     exact masked-key lump, compacted K/V, per-XCD work steal, setprio.

#define MASK_FILL -1e-07f

typedef unsigned short u16;
typedef __attribute__((ext_vector_type(8))) short short8;
typedef __attribute__((ext_vector_type(4))) float f32x4;
typedef __attribute__((ext_vector_type(4))) u16 u16x4;

#define NB 64
#define LL 1024
#define DD 256
#define BQ 128
#define BK 32
#define ELEMS ((size_t)NB * LL * DD)
#define NIT_STREAM 128   // items per stream: qt(8) x dir(2) x boct(8)

__device__ __forceinline__ unsigned bf16_rne(float f) {
    unsigned u = __float_as_uint(f);
    return (u + 0x7fffu + ((u >> 16) & 1u)) >> 16;
}

__device__ __forceinline__ void gll16(const u16* g, u16* l) {
    __builtin_amdgcn_global_load_lds(
        (const __attribute__((address_space(1))) void*)g,
        (__attribute__((address_space(3))) void*)l, 16, 0, 0);
}

// ---- mask dtype detection + normalization ----------------------------------
__global__ __launch_bounds__(256) void mask_detect(
    const unsigned* __restrict__ m1, const unsigned* __restrict__ m2,
    int* __restrict__ flag)
{
    unsigned acc = 0;
    for (int i = threadIdx.x; i < 4096; i += 256)
        acc |= (m1[i] | m2[i]) & ~1u;
    __shared__ unsigned red[256];
    red[threadIdx.x] = acc;
    __syncthreads();
    for (int o = 128; o; o >>= 1) {
        if (threadIdx.x < o) red[threadIdx.x] |= red[threadIdx.x + o];
        __syncthreads();
    }
    if (threadIdx.x == 0) *flag = red[0] ? 1 : 0;
}

__global__ __launch_bounds__(256) void mask_convert(
    const void* __restrict__ m, const int* __restrict__ flag,
    int* __restrict__ outm)
{
    int i = blockIdx.x * 256 + threadIdx.x;
    int v;
    if (*flag) v = ((const unsigned char*)m)[i];
    else       v = ((const int*)m)[i];
    outm[i] = v ? 1 : 0;
}

// ---- zero only the masked output rows ---------------------------------------
__global__ __launch_bounds__(256) void zero_rows(
    const int* __restrict__ cm1, const int* __restrict__ cm2,
    float* __restrict__ out)
{
    int r = blockIdx.x * 8 + (threadIdx.x >> 5);
    int c = (threadIdx.x & 31) * 8;
    int m = (r < NB * LL) ? cm1[r] : cm2[r - NB * LL];
    if (m) {
        f32x4 z4 = {0.f, 0.f, 0.f, 0.f};
        *(f32x4*)(out + (size_t)r * DD + c) = z4;
        *(f32x4*)(out + (size_t)r * DD + c + 4) = z4;
    }
}

// ---- per-batch compaction: qidx (ordered unmasked rows), posAll, qcnt -------
__global__ __launch_bounds__(256) void build_qidx(
    const int* __restrict__ mask, int* __restrict__ qidx,
    int* __restrict__ posAll, int* __restrict__ qcnt)
{
    int b = blockIdx.x, tid = threadIdx.x;
    __shared__ int ps[256];
    const int* mb = mask + b * LL;
    int f[4], s = 0;
#pragma unroll
    for (int j = 0; j < 4; ++j) { f[j] = (mb[tid * 4 + j] == 0) ? 1 : 0; s += f[j]; }
    ps[tid] = s;
    __syncthreads();
    for (int off = 1; off < 256; off <<= 1) {
        int v = (tid >= off) ? ps[tid - off] : 0;
        __syncthreads();
        ps[tid] += v;
        __syncthreads();
    }
    int pos = (tid > 0) ? ps[tid - 1] : 0;
#pragma unroll
    for (int j = 0; j < 4; ++j) {
        posAll[b * LL + tid * 4 + j] = pos;
        if (f[j]) qidx[b * LL + (pos++)] = tid * 4 + j;
    }
    if (tid == 255) qcnt[b] = ps[255];
}

// ---- prep: fp32 -> (hi,lo) bf16 COMPACTED rows + compacted transpose + ------
// ---- deterministic per-tile masked-V partial sums ---------------------------
__global__ __launch_bounds__(256) void prep2_kernel(
    const float* __restrict__ x1, u16* __restrict__ h1, u16* __restrict__ l1,
    u16* __restrict__ t1, const int* __restrict__ cm1,
    const int* __restrict__ pa1, const int* __restrict__ qi1,
    const int* __restrict__ qc1,
    const float* __restrict__ x2, u16* __restrict__ h2, u16* __restrict__ l2,
    u16* __restrict__ t2, const int* __restrict__ cm2,
    const int* __restrict__ pa2, const int* __restrict__ qi2,
    const int* __restrict__ qc2,
    float* __restrict__ part)   // [2][NB][16][256]
{
    __shared__ u16 t[64][65];
    __shared__ float ps2[16][68];
    int blk = blockIdx.x;
    int tensor = blk >> 12;
    blk &= 4095;
    const float* x = tensor ? x2 : x1;
    u16* h  = tensor ? h2 : h1;
    u16* lo = tensor ? l2 : l1;
    u16* xt = tensor ? t2 : t1;
    const int* cm = tensor ? cm2 : cm1;
    const int* pa = tensor ? pa2 : pa1;
    const int* qi = tensor ? qi2 : qi1;
    const int* qc = tensor ? qc2 : qc1;
    int b = blk >> 6, lt = (blk >> 2) & 15, dt = blk & 3;
    int l0 = lt * 64, d0 = dt * 64;
    int tid = threadIdx.x;
    int sub = tid >> 4;
    int c16 = tid & 15;
    float vpart[4] = {0.f, 0.f, 0.f, 0.f};
#pragma unroll
    for (int p = 0; p < 4; ++p) {
        int row = p * 16 + sub;
        int l = l0 + row;
        int masked = cm[b * LL + l];
        int slot = pa[b * LL + l];
        f32x4 v = *(const f32x4*)(x + ((size_t)b * LL + l) * DD + d0 + c16 * 4);
        u16x4 hv, lv;
#pragma unroll
        for (int e = 0; e < 4; ++e) {
            unsigned hb = bf16_rne(v[e]);
            float hf = __uint_as_float(hb << 16);
            unsigned lb = bf16_rne(v[e] - hf);
            hv[e] = (u16)hb;
            lv[e] = (u16)lb;
            t[c16 * 4 + e][row] = (u16)hb;
            if (masked) vpart[e] += v[e];
        }
        if (!masked) {
            size_t gi = ((size_t)b * LL + slot) * DD + d0 + c16 * 4;
            *(u16x4*)(h + gi) = hv;
            *(u16x4*)(lo + gi) = lv;
        }
    }
#pragma unroll
    for (int e = 0; e < 4; ++e) ps2[sub][c16 * 4 + e] = vpart[e];
    __syncthreads();
    int pos_base = pa[b * LL + l0];
    int cntb = qc[b];
    int nun = ((lt == 15) ? cntb : pa[b * LL + l0 + 64]) - pos_base;
#pragma unroll
    for (int p = 0; p < 4; ++p) {
        int d = p * 16 + sub;
#pragma unroll
        for (int e = 0; e < 4; ++e) {
            int j = c16 * 4 + e;
            if (j < nun) {
                int col = qi[b * LL + pos_base + j] - l0;
                xt[((size_t)b * DD + d0 + d) * LL + pos_base + j] = t[d][col];
            }
        }
    }
    if (tid < 64) {
        float s = 0.f;
#pragma unroll
        for (int k = 0; k < 16; ++k) s += ps2[k][tid];
        part[(((size_t)tensor * NB + b) * 16 + lt) * 256 + d0 + tid] = s;
    }
}

// ---- reduce per-tile partials -> Vsum[tensor][b][256] (fixed order) ---------
__global__ __launch_bounds__(256) void vsum_reduce(
    const float* __restrict__ part, float* __restrict__ vsum)
{
    int blk = blockIdx.x;       // tensor*NB + b
    int d = threadIdx.x;
    float s = 0.f;
#pragma unroll
    for (int lt = 0; lt < 16; ++lt)
        s += part[((size_t)blk * 16 + lt) * 256 + d];
    vsum[(size_t)blk * DD + d] = s;
}

// ---- persistent fused flash: 3-pass QK, 80KB split-buffer, 2 blocks/CU ------
// 512 blocks x 512 thr. stream = blockIdx&7 -> batches b%8 (XCD L2 locality).
// NOTE: min-waves arg MUST be 2 (cap 256 regs). 4 caps at 128 -> o[16] spills
// to scratch (R8: FETCH 640MB, 2.6x slower). Natural ~116 regs still yields
// 4 waves/SIMD = 2 blocks/CU.
__global__ __launch_bounds__(512, 2) void flash_fused(
    const u16* __restrict__ v1h, const u16* __restrict__ v1l,
    const u16* __restrict__ v2h, const u16* __restrict__ v2l,
    const u16* __restrict__ v1t, const u16* __restrict__ v2t,
    const int* __restrict__ qidx1, const int* __restrict__ qcnt1,
    const int* __restrict__ qidx2, const int* __restrict__ qcnt2,
    const float* __restrict__ vsum, int* __restrict__ ctr,
    float* __restrict__ out)
{
    int strm0 = blockIdx.x & 7;
    int tid = threadIdx.x;
    int w = tid >> 6, lane = tid & 63;
    int lq = lane & 15, g = lane >> 4;

    // 80KB total: kh 2x16KB + vt 2x16KB + kl 1x16KB. sh_it aliased into kls.
    __shared__ __align__(16) u16 kh2[2][BK * DD];  // [key][d], chunk ^ (key&7)
    __shared__ __align__(16) u16 vt2[2][BK * DD];  // [d][key], chunk ^ (d&3)^((d>>2)&3)
    __shared__ __align__(16) u16 kls[BK * DD];     // kl single buffer

    const int pvcc = (g ^ (lq & 3) ^ ((lq >> 2) & 3)) * 8;

    // kh/vt: 32 x 1KB units, 4/wave. kl: 16 x 1KB units, 2/wave.
#define STAGE_KHVT(PKH, PVT, KT, KVB, VTB, KHG, VTG)                            \
    {                                                                           \
        int k0s = (KT) * BK;                                                    \
        _Pragma("unroll")                                                       \
        for (int t = 0; t < 4; ++t) {                                           \
            int u = t * 8 + w;                                                  \
            int n = u & 15;                                                     \
            if (u < 16) {                                                       \
                unsigned phys = (unsigned)n * 1024u + (unsigned)lane * 16u;     \
                unsigned key = phys >> 9;                                       \
                unsigned cl = ((phys >> 4) & 31u) ^ (key & 7u);                 \
                size_t koff = (KVB) + (size_t)(k0s + (int)key) * DD + cl * 8;   \
                gll16((KHG) + koff, (PKH) + n * 512);                           \
            } else {                                                            \
                unsigned dv = (unsigned)n * 16u + ((unsigned)lane >> 2);        \
                unsigned cv = ((unsigned)lane & 3u) ^ (dv & 3u) ^ ((dv >> 2) & 3u); \
                size_t voff = (VTB) + (size_t)dv * LL + (unsigned)k0s + cv * 8; \
                gll16((VTG) + voff, (PVT) + n * 512);                           \
            }                                                                   \
        }                                                                       \
    }
#define STAGE_KL(KT, KVB, KLG)                                                  \
    {                                                                           \
        int k0s = (KT) * BK;                                                    \
        _Pragma("unroll")                                                       \
        for (int t = 0; t < 2; ++t) {                                           \
            int n = t * 8 + w;                                                  \
            unsigned phys = (unsigned)n * 1024u + (unsigned)lane * 16u;         \
            unsigned key = phys >> 9;                                           \
            unsigned cl = ((phys >> 4) & 31u) ^ (key & 7u);                     \
            size_t koff = (KVB) + (size_t)(k0s + (int)key) * DD + cl * 8;       \
            gll16((KLG) + koff, kls + n * 512);                                 \
        }                                                                       \
    }

    for (int ss = 0; ss < 8; ++ss) {
        int s2 = (strm0 + ss) & 7;
        for (;;) {
            __syncthreads();                       // prev item's kls/LDS reads done
            if (tid == 0) *(int*)kls = atomicAdd(&ctr[s2], 1);
            __syncthreads();
            int it = *(const int*)kls;
            __syncthreads();                       // all read sh_it before kls overwrite
            if (it >= NIT_STREAM) break;
            int qt  = it & 7;
            int dir = (it >> 3) & 1;
            int b   = ((it >> 4) << 3) + s2;

            const u16 *qh_g, *ql_g, *kh_g, *kl_g, *vt_g;
            const int *qidx, *qcq, *qck;
            const float* vsp;
            float* ob;
            if (dir == 0) { qh_g=v1h; ql_g=v1l; kh_g=v2h; kl_g=v2l; vt_g=v2t;
                            qidx=qidx1; qcq=qcnt1; qck=qcnt2;
                            vsp = vsum + ((size_t)NB + b) * DD; ob = out; }
            else          { qh_g=v2h; ql_g=v2l; kh_g=v1h; kl_g=v1l; vt_g=v1t;
                            qidx=qidx2; qcq=qcnt2; qck=qcnt1;
                            vsp = vsum + (size_t)b * DD; ob = out + ELEMS; }
            int cnt_q = qcq[b];
            if (qt * BQ >= cnt_q) continue;
            int cnt_k = qck[b];
            int nkt = (cnt_k + BK - 1) >> 5;

            int qslot = qt * BQ + w * 16 + lq;
            bool qvalid = qslot < cnt_q;

            // Q fragments from compacted rows (row == qslot)
            const u16* qbh = qh_g + ((size_t)b * LL + qslot) * DD + g * 8;
            const u16* qbl = ql_g + ((size_t)b * LL + qslot) * DD + g * 8;
            short8 qhf[8], qlf[8];
#pragma unroll
            for (int ks = 0; ks < 8; ++ks) {
                qhf[ks] = *(const short8*)(qbh + ks * 32);
                qlf[ks] = *(const short8*)(qbl + ks * 32);
            }

            float m = MASK_FILL, z = 0.f;
            f32x4 o[16];
#pragma unroll
            for (int i2 = 0; i2 < 16; ++i2) o[i2] = (f32x4){0.f, 0.f, 0.f, 0.f};

            const size_t kv_base = (size_t)b * LL * DD;
            const size_t vt_base = (size_t)b * DD * LL;

            if (nkt > 0) {
                u16 *khA = kh2[0], *khB = kh2[1];
                u16 *vtA = vt2[0], *vtB = vt2[1];

                STAGE_KHVT(khA, vtA, 0, kv_base, vt_base, kh_g, vt_g);
                asm volatile("s_waitcnt vmcnt(0)" ::: "memory");
                __builtin_amdgcn_s_barrier();
                __builtin_amdgcn_sched_barrier(0);

                for (int kt = 0; kt < nkt; ++kt) {
                    int k0 = kt * BK;
                    STAGE_KL(kt, kv_base, kl_g);                 // 2 gll (oldest)
                    if (kt + 1 < nkt)
                        STAGE_KHVT(khB, vtB, kt + 1, kv_base, vt_base, kh_g, vt_g);

                    // QK hi: S^T += Kh @ (Qh + Ql), on khA
                    f32x4 sa0 = (f32x4){0.f, 0.f, 0.f, 0.f};
                    f32x4 sa1 = (f32x4){0.f, 0.f, 0.f, 0.f};
                    __builtin_amdgcn_s_setprio(1);
#pragma unroll
                    for (int ks = 0; ks < 8; ++ks) {
                        int cidx = ((ks * 4 + g) ^ (lq & 7)) * 8;
                        short8 kh0 = *(const short8*)&khA[lq * 256 + cidx];
                        short8 kh1 = *(const short8*)&khA[(16 + lq) * 256 + cidx];
                        sa0 = __builtin_amdgcn_mfma_f32_16x16x32_bf16(kh0, qhf[ks], sa0, 0, 0, 0);
                        sa0 = __builtin_amdgcn_mfma_f32_16x16x32_bf16(kh0, qlf[ks], sa0, 0, 0, 0);
                        sa1 = __builtin_amdgcn_mfma_f32_16x16x32_bf16(kh1, qhf[ks], sa1, 0, 0, 0);
                        sa1 = __builtin_amdgcn_mfma_f32_16x16x32_bf16(kh1, qlf[ks], sa1, 0, 0, 0);
                    }
                    __builtin_amdgcn_s_setprio(0);

                    // kl landed (its 2 loads are oldest; 4 khvt may remain)
                    if (kt + 1 < nkt) {
                        asm volatile("s_waitcnt vmcnt(4)" ::: "memory");
                    } else {
                        asm volatile("s_waitcnt vmcnt(0)" ::: "memory");
                    }
                    __builtin_amdgcn_s_barrier();
                    __builtin_amdgcn_sched_barrier(0);

                    // QK lo: S^T += Kl @ Qh, on kls
                    __builtin_amdgcn_s_setprio(1);
#pragma unroll
                    for (int ks = 0; ks < 8; ++ks) {
                        int cidx = ((ks * 4 + g) ^ (lq & 7)) * 8;
                        short8 kl0 = *(const short8*)&kls[lq * 256 + cidx];
                        short8 kl1 = *(const short8*)&kls[(16 + lq) * 256 + cidx];
                        sa0 = __builtin_amdgcn_mfma_f32_16x16x32_bf16(kl0, qhf[ks], sa0, 0, 0, 0);
                        sa1 = __builtin_amdgcn_mfma_f32_16x16x32_bf16(kl1, qhf[ks], sa1, 0, 0, 0);
                    }
                    __builtin_amdgcn_s_setprio(0);

                    float s[8];
#pragma unroll
                    for (int i2 = 0; i2 < 4; ++i2) { s[i2] = sa0[i2]; s[4 + i2] = sa1[i2]; }
                    if (kt == nkt - 1) {             // tail clamp: fake keys -> -inf
                        int base = k0 + 4 * g;
#pragma unroll
                        for (int i2 = 0; i2 < 4; ++i2) {
                            if (base + i2 >= cnt_k)      s[i2]     = -1e30f;
                            if (base + 16 + i2 >= cnt_k) s[4 + i2] = -1e30f;
                        }
                    }
                    float pmax = s[0];
#pragma unroll
                    for (int i2 = 1; i2 < 8; ++i2) pmax = fmaxf(pmax, s[i2]);
                    pmax = fmaxf(pmax, __shfl_xor(pmax, 16));
                    pmax = fmaxf(pmax, __shfl_xor(pmax, 32));
                    if (__any(pmax > m)) {
                        float mnew = fmaxf(m, pmax);
                        float alpha = __expf(m - mnew);
                        z *= alpha;
#pragma unroll
                        for (int i2 = 0; i2 < 16; ++i2) o[i2] *= alpha;
                        m = mnew;
                    }
                    float p[8], ps = 0.f;
#pragma unroll
                    for (int i2 = 0; i2 < 8; ++i2) { p[i2] = __expf(s[i2] - m); ps += p[i2]; }
                    ps += __shfl_xor(ps, 16);
                    ps += __shfl_xor(ps, 32);
                    z += ps;

                    unsigned pk00 = bf16_rne(p[0]) | (bf16_rne(p[1]) << 16);
                    unsigned pk01 = bf16_rne(p[2]) | (bf16_rne(p[3]) << 16);
                    unsigned pk10 = bf16_rne(p[4]) | (bf16_rne(p[5]) << 16);
                    unsigned pk11 = bf16_rne(p[6]) | (bf16_rne(p[7]) << 16);
                    int srcA = ((lane & 16) << 1) | lq;
                    int srcB = srcA + 16;
                    unsigned a00 = (unsigned)__shfl((int)pk00, srcA);
                    unsigned a01 = (unsigned)__shfl((int)pk01, srcA);
                    unsigned a10 = (unsigned)__shfl((int)pk10, srcA);
                    unsigned a11 = (unsigned)__shfl((int)pk11, srcA);
                    unsigned b00 = (unsigned)__shfl((int)pk00, srcB);
                    unsigned b01 = (unsigned)__shfl((int)pk01, srcB);
                    unsigned b10 = (unsigned)__shfl((int)pk10, srcB);
                    unsigned b11 = (unsigned)__shfl((int)pk11, srcB);
                    bool sel = (g >> 1) != 0;
                    union { unsigned u[4]; short8 v; } pf;
                    pf.u[0] = sel ? a10 : a00;
                    pf.u[1] = sel ? a11 : a01;
                    pf.u[2] = sel ? b10 : b00;
                    pf.u[3] = sel ? b11 : b01;

                    __builtin_amdgcn_s_setprio(1);
#pragma unroll
                    for (int dt = 0; dt < 16; ++dt) {
                        int d = dt * 16 + lq;
                        short8 vf = *(const short8*)&vtA[d * 32 + pvcc];
                        o[dt] = __builtin_amdgcn_mfma_f32_16x16x32_bf16(vf, pf.v, o[dt], 0, 0, 0);
                    }
                    __builtin_amdgcn_s_setprio(0);

                    if (kt + 1 < nkt) {
                        // khvt(kt+1) issued a full body ago -> near-free drain
                        asm volatile("s_waitcnt vmcnt(0)" ::: "memory");
                        __builtin_amdgcn_s_barrier();
                        __builtin_amdgcn_sched_barrier(0);
                    }
                    u16* tp;
                    tp = khA; khA = khB; khB = tp;
                    tp = vtA; vtA = vtB; vtB = tp;
                }
            }

            // exact masked-key lump: all masked logits == MASK_FILL
            float wl = __expf(MASK_FILL - m);      // m >= MASK_FILL always
            z += (float)(LL - cnt_k) * wl;
#pragma unroll
            for (int dt = 0; dt < 16; ++dt) {
                f32x4 vv = *(const f32x4*)(vsp + dt * 16 + 4 * g);
                o[dt] += wl * vv;
            }

            if (qvalid) {
                int qrow = qidx[b * LL + qslot];
                float zinv = 1.0f / z;
                float* orow = ob + ((size_t)b * LL + qrow) * DD + 4 * g;
#pragma unroll
                for (int dt = 0; dt < 16; ++dt) {
                    f32x4 vv = o[dt] * zinv;
                    *(f32x4*)(orow + dt * 16) = vv;
                }
            }
        }
    }
#undef STAGE_KHVT
#undef STAGE_KL
}

extern "C" void kernel_launch(void* const* d_in, const int* in_sizes, int n_in,
                              void* d_out, int out_size, void* d_ws, size_t ws_size,
                              hipStream_t stream)
{
    const float* v1      = (const float*)d_in[0];
    const void*  v1_mask = d_in[1];
    const float* v2      = (const float*)d_in[2];
    const void*  v2_mask = d_in[3];
    float* out = (float*)d_out;

    u16* v1h = (u16*)d_ws;           // compacted hi (row = compact slot)
    u16* v1l = v1h + ELEMS;
    u16* v2h = v1l + ELEMS;
    u16* v2l = v2h + ELEMS;
    u16* v1t = v2l + ELEMS;          // compacted transpose [b][d][slot]
    u16* v2t = v1t + ELEMS;
    int* qidx1 = (int*)(v2t + ELEMS);
    int* qcnt1 = qidx1 + NB * LL;
    int* qidx2 = qcnt1 + NB;
    int* qcnt2 = qidx2 + NB * LL;
    int* cm1   = qcnt2 + NB;
    int* cm2   = cm1 + NB * LL;
    int* pa1   = cm2 + NB * LL;
    int* pa2   = pa1 + NB * LL;
    int* mflag = pa2 + NB * LL;
    float* part = (float*)(mflag + 16);          // [2][NB][16][256]
    float* vsum = part + 2 * NB * 16 * 256;      // [2][NB][256]
    int* ctr    = (int*)(vsum + 2 * NB * 256);   // [8] steal counters

    hipMemsetAsync(ctr, 0, 8 * sizeof(int), stream);

    mask_detect<<<dim3(1), dim3(256), 0, stream>>>(
        (const unsigned*)v1_mask, (const unsigned*)v2_mask, mflag);
    mask_convert<<<dim3(NB * LL / 256), dim3(256), 0, stream>>>(v1_mask, mflag, cm1);
    mask_convert<<<dim3(NB * LL / 256), dim3(256), 0, stream>>>(v2_mask, mflag, cm2);

    zero_rows<<<dim3(2 * NB * LL / 8), dim3(256), 0, stream>>>(cm1, cm2, out);
    build_qidx<<<dim3(NB), dim3(256), 0, stream>>>(cm1, qidx1, pa1, qcnt1);
    build_qidx<<<dim3(NB), dim3(256), 0, stream>>>(cm2, qidx2, pa2, qcnt2);

    prep2_kernel<<<dim3(2 * NB * 64), dim3(256), 0, stream>>>(
        v1, v1h, v1l, v1t, cm1, pa1, qidx1, qcnt1,
        v2, v2h, v2l, v2t, cm2, pa2, qidx2, qcnt2, part);
    vsum_reduce<<<dim3(2 * NB), dim3(256), 0, stream>>>(part, vsum);

    // persistent, work-stealing fused flash (2 blocks per CU, 80KB LDS each)
    flash_fused<<<dim3(512), dim3(512), 0, stream>>>(
        v1h, v1l, v2h, v2l, v1t, v2t,
        qidx1, qcnt1, qidx2, qcnt2, vsum, ctr, out);
}

// Round 10
// 247.355 us; speedup vs baseline: 2.1458x; 1.2248x over previous
//
#include <hip/hip_runtime.h>
#include <hip/hip_bf16.h>
#include <hip/hip_fp16.h>
#include <stdint.h>

// BidirectionalAttention2: two flash-attention passes over sim = v1 @ v2^T.
// R10: full fp16 pipeline (was bf16). fp16's 10-bit mantissa lets the QK GEMM
//      run 2-pass (kh*qh + kh*ql, K single-fp16): dropped-term std 2.3e-3
//      (8x smaller than R7's failed bf16 2-pass) -> predicted absmax ~0.03.
//      kl tile eliminated -> LDS = kh+vt dbuf = EXACTLY 64KB -> 2 blocks/CU
//      (R9 showed 80KB does NOT pack 2/CU; 160KiB CU needs <=64KB blocks).
//      fp16 P and V also cut the PV quantization error 8x.
//      __launch_bounds__(512,2): NEVER cap regs below 256 (R8 spill lesson).
//      Kept: exact masked-key lump, compacted K/V, per-XCD work steal,
//      setprio, R7's 1-barrier/kt depth-1 schedule (drain overlapped by the
//      co-resident block). zero_rows folded into prep2.

#define MASK_FILL -1e-07f

typedef unsigned short u16;
typedef _Float16 half8 __attribute__((ext_vector_type(8)));
typedef __attribute__((ext_vector_type(4))) float f32x4;
typedef __attribute__((ext_vector_type(4))) u16 u16x4;

#define NB 64
#define LL 1024
#define DD 256
#define BQ 128
#define BK 32
#define ELEMS ((size_t)NB * LL * DD)
#define NIT_STREAM 128   // items per stream: qt(8) x dir(2) x boct(8)

__device__ __forceinline__ u16 f16b(float f) {
    _Float16 h = (_Float16)f;
    return __builtin_bit_cast(u16, h);
}
__device__ __forceinline__ unsigned pkf16(float a, float b) {
    return (unsigned)f16b(a) | ((unsigned)f16b(b) << 16);
}

__device__ __forceinline__ void gll16(const u16* g, u16* l) {
    __builtin_amdgcn_global_load_lds(
        (const __attribute__((address_space(1))) void*)g,
        (__attribute__((address_space(3))) void*)l, 16, 0, 0);
}

// ---- mask dtype detection + normalization ----------------------------------
__global__ __launch_bounds__(256) void mask_detect(
    const unsigned* __restrict__ m1, const unsigned* __restrict__ m2,
    int* __restrict__ flag)
{
    unsigned acc = 0;
    for (int i = threadIdx.x; i < 4096; i += 256)
        acc |= (m1[i] | m2[i]) & ~1u;
    __shared__ unsigned red[256];
    red[threadIdx.x] = acc;
    __syncthreads();
    for (int o = 128; o; o >>= 1) {
        if (threadIdx.x < o) red[threadIdx.x] |= red[threadIdx.x + o];
        __syncthreads();
    }
    if (threadIdx.x == 0) *flag = red[0] ? 1 : 0;
}

__global__ __launch_bounds__(256) void mask_convert(
    const void* __restrict__ m, const int* __restrict__ flag,
    int* __restrict__ outm)
{
    int i = blockIdx.x * 256 + threadIdx.x;
    int v;
    if (*flag) v = ((const unsigned char*)m)[i];
    else       v = ((const int*)m)[i];
    outm[i] = v ? 1 : 0;
}

// ---- per-batch compaction: qidx (ordered unmasked rows), posAll, qcnt -------
__global__ __launch_bounds__(256) void build_qidx(
    const int* __restrict__ mask, int* __restrict__ qidx,
    int* __restrict__ posAll, int* __restrict__ qcnt)
{
    int b = blockIdx.x, tid = threadIdx.x;
    __shared__ int ps[256];
    const int* mb = mask + b * LL;
    int f[4], s = 0;
#pragma unroll
    for (int j = 0; j < 4; ++j) { f[j] = (mb[tid * 4 + j] == 0) ? 1 : 0; s += f[j]; }
    ps[tid] = s;
    __syncthreads();
    for (int off = 1; off < 256; off <<= 1) {
        int v = (tid >= off) ? ps[tid - off] : 0;
        __syncthreads();
        ps[tid] += v;
        __syncthreads();
    }
    int pos = (tid > 0) ? ps[tid - 1] : 0;
#pragma unroll
    for (int j = 0; j < 4; ++j) {
        posAll[b * LL + tid * 4 + j] = pos;
        if (f[j]) qidx[b * LL + (pos++)] = tid * 4 + j;
    }
    if (tid == 255) qcnt[b] = ps[255];
}

// ---- prep: fp32 -> (hi,lo) fp16 COMPACTED rows + compacted fp16 transpose +
// ---- masked-V partial sums + zeroing of masked output rows (fused) ----------
__global__ __launch_bounds__(256) void prep2_kernel(
    const float* __restrict__ x1, u16* __restrict__ h1, u16* __restrict__ l1,
    u16* __restrict__ t1, const int* __restrict__ cm1,
    const int* __restrict__ pa1, const int* __restrict__ qi1,
    const int* __restrict__ qc1,
    const float* __restrict__ x2, u16* __restrict__ h2, u16* __restrict__ l2,
    u16* __restrict__ t2, const int* __restrict__ cm2,
    const int* __restrict__ pa2, const int* __restrict__ qi2,
    const int* __restrict__ qc2,
    float* __restrict__ part, float* __restrict__ out)
{
    __shared__ u16 t[64][65];
    __shared__ float ps2[16][68];
    int blk = blockIdx.x;
    int tensor = blk >> 12;
    blk &= 4095;
    const float* x = tensor ? x2 : x1;
    u16* h  = tensor ? h2 : h1;
    u16* lo = tensor ? l2 : l1;
    u16* xt = tensor ? t2 : t1;
    const int* cm = tensor ? cm2 : cm1;
    const int* pa = tensor ? pa2 : pa1;
    const int* qi = tensor ? qi2 : qi1;
    const int* qc = tensor ? qc2 : qc1;
    float* outb = out + (tensor ? ELEMS : 0);
    int b = blk >> 6, lt = (blk >> 2) & 15, dt = blk & 3;
    int l0 = lt * 64, d0 = dt * 64;
    int tid = threadIdx.x;
    int sub = tid >> 4;
    int c16 = tid & 15;
    float vpart[4] = {0.f, 0.f, 0.f, 0.f};
#pragma unroll
    for (int p = 0; p < 4; ++p) {
        int row = p * 16 + sub;
        int l = l0 + row;
        int masked = cm[b * LL + l];
        int slot = pa[b * LL + l];
        f32x4 v = *(const f32x4*)(x + ((size_t)b * LL + l) * DD + d0 + c16 * 4);
        u16x4 hv, lv;
#pragma unroll
        for (int e = 0; e < 4; ++e) {
            _Float16 hh = (_Float16)v[e];
            float hf = (float)hh;
            hv[e] = __builtin_bit_cast(u16, hh);
            lv[e] = f16b(v[e] - hf);
            t[c16 * 4 + e][row] = hv[e];
            if (masked) vpart[e] += v[e];
        }
        if (!masked) {
            size_t gi = ((size_t)b * LL + slot) * DD + d0 + c16 * 4;
            *(u16x4*)(h + gi) = hv;
            *(u16x4*)(lo + gi) = lv;
        } else {
            // fused zero_rows: masked output rows are zero
            f32x4 z4 = {0.f, 0.f, 0.f, 0.f};
            *(f32x4*)(outb + ((size_t)b * LL + l) * DD + d0 + c16 * 4) = z4;
        }
    }
#pragma unroll
    for (int e = 0; e < 4; ++e) ps2[sub][c16 * 4 + e] = vpart[e];
    __syncthreads();
    int pos_base = pa[b * LL + l0];
    int cntb = qc[b];
    int nun = ((lt == 15) ? cntb : pa[b * LL + l0 + 64]) - pos_base;
#pragma unroll
    for (int p = 0; p < 4; ++p) {
        int d = p * 16 + sub;
#pragma unroll
        for (int e = 0; e < 4; ++e) {
            int j = c16 * 4 + e;
            if (j < nun) {
                int col = qi[b * LL + pos_base + j] - l0;
                xt[((size_t)b * DD + d0 + d) * LL + pos_base + j] = t[d][col];
            }
        }
    }
    if (tid < 64) {
        float s = 0.f;
#pragma unroll
        for (int k = 0; k < 16; ++k) s += ps2[k][tid];
        part[(((size_t)tensor * NB + b) * 16 + lt) * 256 + d0 + tid] = s;
    }
}

// ---- reduce per-tile partials -> Vsum[tensor][b][256] (fixed order) ---------
__global__ __launch_bounds__(256) void vsum_reduce(
    const float* __restrict__ part, float* __restrict__ vsum)
{
    int blk = blockIdx.x;       // tensor*NB + b
    int d = threadIdx.x;
    float s = 0.f;
#pragma unroll
    for (int lt = 0; lt < 16; ++lt)
        s += part[((size_t)blk * 16 + lt) * 256 + d];
    vsum[(size_t)blk * DD + d] = s;
}

// ---- persistent fused flash: fp16 2-pass QK, 64KB LDS, 2 blocks/CU ----------
// 512 blocks x 512 thr. stream = blockIdx&7 -> batches b%8 (XCD L2 locality).
__global__ __launch_bounds__(512, 2) void flash_fused(
    const u16* __restrict__ v1h, const u16* __restrict__ v1l,
    const u16* __restrict__ v2h, const u16* __restrict__ v2l,
    const u16* __restrict__ v1t, const u16* __restrict__ v2t,
    const int* __restrict__ qidx1, const int* __restrict__ qcnt1,
    const int* __restrict__ qidx2, const int* __restrict__ qcnt2,
    const float* __restrict__ vsum, int* __restrict__ ctr,
    float* __restrict__ out)
{
    int strm0 = blockIdx.x & 7;
    int tid = threadIdx.x;
    int w = tid >> 6, lane = tid & 63;
    int lq = lane & 15, g = lane >> 4;

    // EXACTLY 64KB: kh 2x16KB + vt 2x16KB (sh_it aliased into kh2[0]).
    __shared__ __align__(16) u16 kh2[2][BK * DD];  // [key][d], chunk ^ (key&7)
    __shared__ __align__(16) u16 vt2[2][BK * DD];  // [d][key], chunk ^ (d&3)^((d>>2)&3)

    const int pvcc = (g ^ (lq & 3) ^ ((lq >> 2) & 3)) * 8;

    // 32 x 1KB gll units/tile, 4 per wave: u<16 -> kh unit u, else vt unit u-16
#define STAGE(PKH, PVT, KT, KVB, VTB, KHG, VTG)                                 \
    {                                                                           \
        int k0s = (KT) * BK;                                                    \
        _Pragma("unroll")                                                       \
        for (int t = 0; t < 4; ++t) {                                           \
            int u = t * 8 + w;                                                  \
            int n = u & 15;                                                     \
            if (u < 16) {                                                       \
                unsigned phys = (unsigned)n * 1024u + (unsigned)lane * 16u;     \
                unsigned key = phys >> 9;                                       \
                unsigned cl = ((phys >> 4) & 31u) ^ (key & 7u);                 \
                size_t koff = (KVB) + (size_t)(k0s + (int)key) * DD + cl * 8;   \
                gll16((KHG) + koff, (PKH) + n * 512);                           \
            } else {                                                            \
                unsigned dv = (unsigned)n * 16u + ((unsigned)lane >> 2);        \
                unsigned cv = ((unsigned)lane & 3u) ^ (dv & 3u) ^ ((dv >> 2) & 3u); \
                size_t voff = (VTB) + (size_t)dv * LL + (unsigned)k0s + cv * 8; \
                gll16((VTG) + voff, (PVT) + n * 512);                           \
            }                                                                   \
        }                                                                       \
    }

    for (int ss = 0; ss < 8; ++ss) {
        int s2 = (strm0 + ss) & 7;
        for (;;) {
            __syncthreads();                       // prev item's LDS reads done
            if (tid == 0) *(int*)&kh2[0][0] = atomicAdd(&ctr[s2], 1);
            __syncthreads();
            int it = *(const int*)&kh2[0][0];
            __syncthreads();                       // all read it before overwrite
            if (it >= NIT_STREAM) break;
            int qt  = it & 7;
            int dir = (it >> 3) & 1;
            int b   = ((it >> 4) << 3) + s2;

            const u16 *qh_g, *ql_g, *kh_g, *vt_g;
            const int *qidx, *qcq, *qck;
            const float* vsp;
            float* ob;
            if (dir == 0) { qh_g=v1h; ql_g=v1l; kh_g=v2h; vt_g=v2t;
                            qidx=qidx1; qcq=qcnt1; qck=qcnt2;
                            vsp = vsum + ((size_t)NB + b) * DD; ob = out; }
            else          { qh_g=v2h; ql_g=v2l; kh_g=v1h; vt_g=v1t;
                            qidx=qidx2; qcq=qcnt2; qck=qcnt1;
                            vsp = vsum + (size_t)b * DD; ob = out + ELEMS; }
            int cnt_q = qcq[b];
            if (qt * BQ >= cnt_q) continue;
            int cnt_k = qck[b];
            int nkt = (cnt_k + BK - 1) >> 5;

            int qslot = qt * BQ + w * 16 + lq;
            bool qvalid = qslot < cnt_q;

            // Q fragments from compacted rows (row == qslot), fp16 hi/lo
            const u16* qbh = qh_g + ((size_t)b * LL + qslot) * DD + g * 8;
            const u16* qbl = ql_g + ((size_t)b * LL + qslot) * DD + g * 8;
            half8 qhf[8], qlf[8];
#pragma unroll
            for (int ks = 0; ks < 8; ++ks) {
                qhf[ks] = *(const half8*)(const void*)(qbh + ks * 32);
                qlf[ks] = *(const half8*)(const void*)(qbl + ks * 32);
            }

            float m = MASK_FILL, z = 0.f;
            f32x4 o[16];
#pragma unroll
            for (int i2 = 0; i2 < 16; ++i2) o[i2] = (f32x4){0.f, 0.f, 0.f, 0.f};

            const size_t kv_base = (size_t)b * LL * DD;
            const size_t vt_base = (size_t)b * DD * LL;

            if (nkt > 0) {
                u16 *khA = kh2[0], *khB = kh2[1];
                u16 *vtA = vt2[0], *vtB = vt2[1];

                STAGE(khA, vtA, 0, kv_base, vt_base, kh_g, vt_g);
                asm volatile("s_waitcnt vmcnt(0)" ::: "memory");
                __builtin_amdgcn_s_barrier();
                __builtin_amdgcn_sched_barrier(0);

                for (int kt = 0; kt < nkt; ++kt) {
                    int k0 = kt * BK;
                    if (kt + 1 < nkt)
                        STAGE(khB, vtB, kt + 1, kv_base, vt_base, kh_g, vt_g);

                    // S^T = K @ Q^T, 2 passes (K single-fp16, Q hi/lo fp16)
                    f32x4 sa0 = (f32x4){0.f, 0.f, 0.f, 0.f};
                    f32x4 sa1 = (f32x4){0.f, 0.f, 0.f, 0.f};
                    __builtin_amdgcn_s_setprio(1);
#pragma unroll
                    for (int ks = 0; ks < 8; ++ks) {
                        int cidx = ((ks * 4 + g) ^ (lq & 7)) * 8;
                        half8 kh0 = *(const half8*)(const void*)&khA[lq * 256 + cidx];
                        half8 kh1 = *(const half8*)(const void*)&khA[(16 + lq) * 256 + cidx];
                        sa0 = __builtin_amdgcn_mfma_f32_16x16x32_f16(kh0, qhf[ks], sa0, 0, 0, 0);
                        sa0 = __builtin_amdgcn_mfma_f32_16x16x32_f16(kh0, qlf[ks], sa0, 0, 0, 0);
                        sa1 = __builtin_amdgcn_mfma_f32_16x16x32_f16(kh1, qhf[ks], sa1, 0, 0, 0);
                        sa1 = __builtin_amdgcn_mfma_f32_16x16x32_f16(kh1, qlf[ks], sa1, 0, 0, 0);
                    }
                    __builtin_amdgcn_s_setprio(0);

                    float s[8];
#pragma unroll
                    for (int i2 = 0; i2 < 4; ++i2) { s[i2] = sa0[i2]; s[4 + i2] = sa1[i2]; }
                    if (kt == nkt - 1) {             // tail clamp: fake keys -> -inf
                        int base = k0 + 4 * g;
#pragma unroll
                        for (int i2 = 0; i2 < 4; ++i2) {
                            if (base + i2 >= cnt_k)      s[i2]     = -1e30f;
                            if (base + 16 + i2 >= cnt_k) s[4 + i2] = -1e30f;
                        }
                    }
                    float pmax = s[0];
#pragma unroll
                    for (int i2 = 1; i2 < 8; ++i2) pmax = fmaxf(pmax, s[i2]);
                    pmax = fmaxf(pmax, __shfl_xor(pmax, 16));
                    pmax = fmaxf(pmax, __shfl_xor(pmax, 32));
                    if (__any(pmax > m)) {
                        float mnew = fmaxf(m, pmax);
                        float alpha = __expf(m - mnew);
                        z *= alpha;
#pragma unroll
                        for (int i2 = 0; i2 < 16; ++i2) o[i2] *= alpha;
                        m = mnew;
                    }
                    float p[8], ps = 0.f;
#pragma unroll
                    for (int i2 = 0; i2 < 8; ++i2) { p[i2] = __expf(s[i2] - m); ps += p[i2]; }
                    ps += __shfl_xor(ps, 16);
                    ps += __shfl_xor(ps, 32);
                    z += ps;

                    // P -> PV B-fragment (fp16), in-register exchange
                    unsigned pk00 = pkf16(p[0], p[1]);
                    unsigned pk01 = pkf16(p[2], p[3]);
                    unsigned pk10 = pkf16(p[4], p[5]);
                    unsigned pk11 = pkf16(p[6], p[7]);
                    int srcA = ((lane & 16) << 1) | lq;
                    int srcB = srcA + 16;
                    unsigned a00 = (unsigned)__shfl((int)pk00, srcA);
                    unsigned a01 = (unsigned)__shfl((int)pk01, srcA);
                    unsigned a10 = (unsigned)__shfl((int)pk10, srcA);
                    unsigned a11 = (unsigned)__shfl((int)pk11, srcA);
                    unsigned b00 = (unsigned)__shfl((int)pk00, srcB);
                    unsigned b01 = (unsigned)__shfl((int)pk01, srcB);
                    unsigned b10 = (unsigned)__shfl((int)pk10, srcB);
                    unsigned b11 = (unsigned)__shfl((int)pk11, srcB);
                    bool sel = (g >> 1) != 0;
                    union { unsigned u[4]; half8 v; } pf;
                    pf.u[0] = sel ? a10 : a00;
                    pf.u[1] = sel ? a11 : a01;
                    pf.u[2] = sel ? b10 : b00;
                    pf.u[3] = sel ? b11 : b01;

                    // O^T += V^T @ P^T
                    __builtin_amdgcn_s_setprio(1);
#pragma unroll
                    for (int dt = 0; dt < 16; ++dt) {
                        int d = dt * 16 + lq;
                        half8 vf = *(const half8*)(const void*)&vtA[d * 32 + pvcc];
                        o[dt] = __builtin_amdgcn_mfma_f32_16x16x32_f16(vf, pf.v, o[dt], 0, 0, 0);
                    }
                    __builtin_amdgcn_s_setprio(0);

                    if (kt + 1 < nkt) {
                        // loads issued a full body ago -> near-free drain;
                        // co-resident block covers the residue
                        asm volatile("s_waitcnt vmcnt(0)" ::: "memory");
                        __builtin_amdgcn_s_barrier();
                        __builtin_amdgcn_sched_barrier(0);
                    }
                    u16* tp;
                    tp = khA; khA = khB; khB = tp;
                    tp = vtA; vtA = vtB; vtB = tp;
                }
            }

            // exact masked-key lump: all masked logits == MASK_FILL
            float wl = __expf(MASK_FILL - m);      // m >= MASK_FILL always
            z += (float)(LL - cnt_k) * wl;
#pragma unroll
            for (int dt = 0; dt < 16; ++dt) {
                f32x4 vv = *(const f32x4*)(vsp + dt * 16 + 4 * g);
                o[dt] += wl * vv;
            }

            if (qvalid) {
                int qrow = qidx[b * LL + qslot];
                float zinv = 1.0f / z;
                float* orow = ob + ((size_t)b * LL + qrow) * DD + 4 * g;
#pragma unroll
                for (int dt = 0; dt < 16; ++dt) {
                    f32x4 vv = o[dt] * zinv;
                    *(f32x4*)(orow + dt * 16) = vv;
                }
            }
        }
    }
#undef STAGE
}

extern "C" void kernel_launch(void* const* d_in, const int* in_sizes, int n_in,
                              void* d_out, int out_size, void* d_ws, size_t ws_size,
                              hipStream_t stream)
{
    const float* v1      = (const float*)d_in[0];
    const void*  v1_mask = d_in[1];
    const float* v2      = (const float*)d_in[2];
    const void*  v2_mask = d_in[3];
    float* out = (float*)d_out;

    u16* v1h = (u16*)d_ws;           // compacted fp16 hi (row = compact slot)
    u16* v1l = v1h + ELEMS;          // compacted fp16 lo
    u16* v2h = v1l + ELEMS;
    u16* v2l = v2h + ELEMS;
    u16* v1t = v2l + ELEMS;          // compacted fp16 transpose [b][d][slot]
    u16* v2t = v1t + ELEMS;
    int* qidx1 = (int*)(v2t + ELEMS);
    int* qcnt1 = qidx1 + NB * LL;
    int* qidx2 = qcnt1 + NB;
    int* qcnt2 = qidx2 + NB * LL;
    int* cm1   = qcnt2 + NB;
    int* cm2   = cm1 + NB * LL;
    int* pa1   = cm2 + NB * LL;
    int* pa2   = pa1 + NB * LL;
    int* mflag = pa2 + NB * LL;
    float* part = (float*)(mflag + 16);          // [2][NB][16][256]
    float* vsum = part + 2 * NB * 16 * 256;      // [2][NB][256]
    int* ctr    = (int*)(vsum + 2 * NB * 256);   // [8] steal counters

    hipMemsetAsync(ctr, 0, 8 * sizeof(int), stream);

    mask_detect<<<dim3(1), dim3(256), 0, stream>>>(
        (const unsigned*)v1_mask, (const unsigned*)v2_mask, mflag);
    mask_convert<<<dim3(NB * LL / 256), dim3(256), 0, stream>>>(v1_mask, mflag, cm1);
    mask_convert<<<dim3(NB * LL / 256), dim3(256), 0, stream>>>(v2_mask, mflag, cm2);

    build_qidx<<<dim3(NB), dim3(256), 0, stream>>>(cm1, qidx1, pa1, qcnt1);
    build_qidx<<<dim3(NB), dim3(256), 0, stream>>>(cm2, qidx2, pa2, qcnt2);

    prep2_kernel<<<dim3(2 * NB * 64), dim3(256), 0, stream>>>(
        v1, v1h, v1l, v1t, cm1, pa1, qidx1, qcnt1,
        v2, v2h, v2l, v2t, cm2, pa2, qidx2, qcnt2, part, out);
    vsum_reduce<<<dim3(2 * NB), dim3(256), 0, stream>>>(part, vsum);

    // persistent, work-stealing fused flash (target: 2 blocks/CU @ 64KB LDS)
    flash_fused<<<dim3(512), dim3(512), 0, stream>>>(
        v1h, v1l, v2h, v2l, v1t, v2t,
        qidx1, qcnt1, qidx2, qcnt2, vsum, ctr, out);
}

// Round 11
// 213.055 us; speedup vs baseline: 2.4913x; 1.1610x over previous
//
#include <hip/hip_runtime.h>
#include <hip/hip_bf16.h>
#include <hip/hip_fp16.h>
#include <stdint.h>

// BidirectionalAttention2: two flash-attention passes over sim = v1 @ v2^T.
// R11: (1) BK=64 per barrier via TWO 32-key sub-tiles (identical layouts to
//      R10) -> halves barriers/waits/softmax fixed cost per key. LDS 128KB,
//      1 block/CU (R10 showed unified VGPR+AGPR ~168 caps at 1 block anyway).
//      (2) single-pass fp16 QK (Q single fp16): extra logit err std ~4.5e-3
//      (R7 anchor: bf16's 0.036 -> absmax 0.144; ratio 4 -> predicted ~0.05).
//      PRE-COMMIT: absmax>0.09 -> revert to 2-pass.
//      (3) mask detect/convert/qidx fused into one kernel; ctr memset folded.
//      Kept: exact masked-key lump, compacted K/V, work steal, setprio.

#define MASK_FILL -1e-07f

typedef unsigned short u16;
typedef _Float16 half8 __attribute__((ext_vector_type(8)));
typedef __attribute__((ext_vector_type(4))) float f32x4;
typedef __attribute__((ext_vector_type(4))) u16 u16x4;

#define NB 64
#define LL 1024
#define DD 256
#define BQ 128
#define HB 32                 // half-block of keys (sub-tile)
#define ELEMS ((size_t)NB * LL * DD)
#define NIT_STREAM 128        // items per stream: qt(8) x dir(2) x boct(8)

__device__ __forceinline__ u16 f16b(float f) {
    _Float16 h = (_Float16)f;
    return __builtin_bit_cast(u16, h);
}
__device__ __forceinline__ unsigned pkf16(float a, float b) {
    return (unsigned)f16b(a) | ((unsigned)f16b(b) << 16);
}

__device__ __forceinline__ void gll16(const u16* g, u16* l) {
    __builtin_amdgcn_global_load_lds(
        (const __attribute__((address_space(1))) void*)g,
        (__attribute__((address_space(3))) void*)l, 16, 0, 0);
}

// ---- fused: mask dtype detect + convert + per-batch compaction + ctr clear --
// grid 128: msk = blk>>6, b = blk&63. Detection is over a fixed window of
// both masks -> every block computes the same flag (deterministic).
__global__ __launch_bounds__(256) void prep_masks(
    const void* __restrict__ m1, const void* __restrict__ m2,
    int* __restrict__ cm1, int* __restrict__ cm2,
    int* __restrict__ qidx1, int* __restrict__ pa1, int* __restrict__ qcnt1,
    int* __restrict__ qidx2, int* __restrict__ pa2, int* __restrict__ qcnt2,
    int* __restrict__ ctr)
{
    int blk = blockIdx.x, tid = threadIdx.x;
    int msk = blk >> 6, b = blk & 63;
    // dtype detect: int32 0/1 has no bits above bit0; packed bool does (16KB window)
    const unsigned* w1 = (const unsigned*)m1;
    const unsigned* w2 = (const unsigned*)m2;
    unsigned acc = 0;
    for (int i = tid; i < 4096; i += 256) acc |= (w1[i] | w2[i]) & ~1u;
    __shared__ unsigned red[256];
    red[tid] = acc;
    __syncthreads();
    for (int o = 128; o; o >>= 1) {
        if (tid < o) red[tid] |= red[tid + o];
        __syncthreads();
    }
    int isbool = red[0] ? 1 : 0;

    const void* m = msk ? m2 : m1;
    int* cm   = msk ? cm2 : cm1;
    int* qidx = msk ? qidx2 : qidx1;
    int* pa   = msk ? pa2 : pa1;
    int* qcnt = msk ? qcnt2 : qcnt1;

    __shared__ int ps[256];
    int f[4], s = 0;
#pragma unroll
    for (int j = 0; j < 4; ++j) {
        int idx = b * LL + tid * 4 + j;
        int v = isbool ? (int)((const unsigned char*)m)[idx] : ((const int*)m)[idx];
        cm[idx] = v ? 1 : 0;
        f[j] = (v == 0) ? 1 : 0;
        s += f[j];
    }
    ps[tid] = s;
    __syncthreads();
    for (int off = 1; off < 256; off <<= 1) {
        int v = (tid >= off) ? ps[tid - off] : 0;
        __syncthreads();
        ps[tid] += v;
        __syncthreads();
    }
    int pos = (tid > 0) ? ps[tid - 1] : 0;
#pragma unroll
    for (int j = 0; j < 4; ++j) {
        pa[b * LL + tid * 4 + j] = pos;
        if (f[j]) qidx[b * LL + (pos++)] = tid * 4 + j;
    }
    if (tid == 255) qcnt[b] = ps[255];
    if (blk == 0 && tid < 8) ctr[tid] = 0;
}

// ---- prep: fp32 -> fp16 COMPACTED rows + compacted fp16 transpose +
// ---- masked-V partial sums + zeroing of masked output rows (fused) ----------
__global__ __launch_bounds__(256) void prep2_kernel(
    const float* __restrict__ x1, u16* __restrict__ h1, u16* __restrict__ t1,
    const int* __restrict__ cm1, const int* __restrict__ pa1,
    const int* __restrict__ qi1, const int* __restrict__ qc1,
    const float* __restrict__ x2, u16* __restrict__ h2, u16* __restrict__ t2,
    const int* __restrict__ cm2, const int* __restrict__ pa2,
    const int* __restrict__ qi2, const int* __restrict__ qc2,
    float* __restrict__ part, float* __restrict__ out)
{
    __shared__ u16 t[64][65];
    __shared__ float ps2[16][68];
    int blk = blockIdx.x;
    int tensor = blk >> 12;
    blk &= 4095;
    const float* x = tensor ? x2 : x1;
    u16* h  = tensor ? h2 : h1;
    u16* xt = tensor ? t2 : t1;
    const int* cm = tensor ? cm2 : cm1;
    const int* pa = tensor ? pa2 : pa1;
    const int* qi = tensor ? qi2 : qi1;
    const int* qc = tensor ? qc2 : qc1;
    float* outb = out + (tensor ? ELEMS : 0);
    int b = blk >> 6, lt = (blk >> 2) & 15, dt = blk & 3;
    int l0 = lt * 64, d0 = dt * 64;
    int tid = threadIdx.x;
    int sub = tid >> 4;
    int c16 = tid & 15;
    float vpart[4] = {0.f, 0.f, 0.f, 0.f};
#pragma unroll
    for (int p = 0; p < 4; ++p) {
        int row = p * 16 + sub;
        int l = l0 + row;
        int masked = cm[b * LL + l];
        int slot = pa[b * LL + l];
        f32x4 v = *(const f32x4*)(x + ((size_t)b * LL + l) * DD + d0 + c16 * 4);
        u16x4 hv;
#pragma unroll
        for (int e = 0; e < 4; ++e) {
            hv[e] = f16b(v[e]);
            t[c16 * 4 + e][row] = hv[e];
            if (masked) vpart[e] += v[e];
        }
        if (!masked) {
            *(u16x4*)(h + ((size_t)b * LL + slot) * DD + d0 + c16 * 4) = hv;
        } else {
            f32x4 z4 = {0.f, 0.f, 0.f, 0.f};
            *(f32x4*)(outb + ((size_t)b * LL + l) * DD + d0 + c16 * 4) = z4;
        }
    }
#pragma unroll
    for (int e = 0; e < 4; ++e) ps2[sub][c16 * 4 + e] = vpart[e];
    __syncthreads();
    int pos_base = pa[b * LL + l0];
    int cntb = qc[b];
    int nun = ((lt == 15) ? cntb : pa[b * LL + l0 + 64]) - pos_base;
#pragma unroll
    for (int p = 0; p < 4; ++p) {
        int d = p * 16 + sub;
#pragma unroll
        for (int e = 0; e < 4; ++e) {
            int j = c16 * 4 + e;
            if (j < nun) {
                int col = qi[b * LL + pos_base + j] - l0;
                xt[((size_t)b * DD + d0 + d) * LL + pos_base + j] = t[d][col];
            }
        }
    }
    if (tid < 64) {
        float s = 0.f;
#pragma unroll
        for (int k = 0; k < 16; ++k) s += ps2[k][tid];
        part[(((size_t)tensor * NB + b) * 16 + lt) * 256 + d0 + tid] = s;
    }
}

// ---- reduce per-tile partials -> Vsum[tensor][b][256] (fixed order) ---------
__global__ __launch_bounds__(256) void vsum_reduce(
    const float* __restrict__ part, float* __restrict__ vsum)
{
    int blk = blockIdx.x;       // tensor*NB + b
    int d = threadIdx.x;
    float s = 0.f;
#pragma unroll
    for (int lt = 0; lt < 16; ++lt)
        s += part[((size_t)blk * 16 + lt) * 256 + d];
    vsum[(size_t)blk * DD + d] = s;
}

// ---- persistent fused flash: fp16 1-pass QK, 64 keys/barrier, 128KB LDS -----
// 256 blocks x 512 thr (1/CU). stream = blockIdx&7 -> batches b%8.
__global__ __launch_bounds__(512, 2) void flash_fused(
    const u16* __restrict__ v1h, const u16* __restrict__ v2h,
    const u16* __restrict__ v1t, const u16* __restrict__ v2t,
    const int* __restrict__ qidx1, const int* __restrict__ qcnt1,
    const int* __restrict__ qidx2, const int* __restrict__ qcnt2,
    const float* __restrict__ vsum, int* __restrict__ ctr,
    float* __restrict__ out)
{
    int strm0 = blockIdx.x & 7;
    int tid = threadIdx.x;
    int w = tid >> 6, lane = tid & 63;
    int lq = lane & 15, g = lane >> 4;

    // 128KB: [buf][half] 16KB sub-tiles, layouts identical to the 32-key ver.
    __shared__ __align__(16) u16 khs[2][2][HB * DD];  // [key][d], chunk ^ (key&7)
    __shared__ __align__(16) u16 vts[2][2][HB * DD];  // [d][key], chunk ^ (d&3)^((d>>2)&3)

    const int pvcc = (g ^ (lq & 3) ^ ((lq >> 2) & 3)) * 8;

    // 64 x 1KB gll units per 64-key tile, 8 per wave:
    // u<16: kh half0 | 16..31: kh half1 | 32..47: vt half0 | 48..63: vt half1
#define STAGE(BUF, KT2)                                                         \
    {                                                                           \
        int k0s = (KT2) * 64;                                                   \
        _Pragma("unroll")                                                       \
        for (int t = 0; t < 8; ++t) {                                           \
            int u = t * 8 + w;                                                  \
            int n = u & 15;                                                     \
            int hh = (u >> 4) & 1;                                              \
            if (u < 32) {                                                       \
                unsigned phys = (unsigned)n * 1024u + (unsigned)lane * 16u;     \
                unsigned key = phys >> 9;                                       \
                unsigned cl = ((phys >> 4) & 31u) ^ (key & 7u);                 \
                size_t koff = kv_base + (size_t)(k0s + hh * HB + (int)key) * DD + cl * 8; \
                gll16(kh_g + koff, &khs[BUF][hh][n * 512]);                     \
            } else {                                                            \
                unsigned dv = (unsigned)n * 16u + ((unsigned)lane >> 2);        \
                unsigned cv = ((unsigned)lane & 3u) ^ (dv & 3u) ^ ((dv >> 2) & 3u); \
                size_t voff = vt_base + (size_t)dv * LL + (unsigned)(k0s + hh * HB) + cv * 8; \
                gll16(vt_g + voff, &vts[BUF][hh][n * 512]);                     \
            }                                                                   \
        }                                                                       \
    }

    for (int ss = 0; ss < 8; ++ss) {
        int s2 = (strm0 + ss) & 7;
        for (;;) {
            __syncthreads();                       // prev item's LDS reads done
            if (tid == 0) *(int*)&khs[0][0][0] = atomicAdd(&ctr[s2], 1);
            __syncthreads();
            int it = *(const int*)&khs[0][0][0];
            __syncthreads();                       // all read it before overwrite
            if (it >= NIT_STREAM) break;
            int qt  = it & 7;
            int dir = (it >> 3) & 1;
            int b   = ((it >> 4) << 3) + s2;

            const u16 *qh_g, *kh_g, *vt_g;
            const int *qidx, *qcq, *qck;
            const float* vsp;
            float* ob;
            if (dir == 0) { qh_g=v1h; kh_g=v2h; vt_g=v2t;
                            qidx=qidx1; qcq=qcnt1; qck=qcnt2;
                            vsp = vsum + ((size_t)NB + b) * DD; ob = out; }
            else          { qh_g=v2h; kh_g=v1h; vt_g=v1t;
                            qidx=qidx2; qcq=qcnt2; qck=qcnt1;
                            vsp = vsum + (size_t)b * DD; ob = out + ELEMS; }
            int cnt_q = qcq[b];
            if (qt * BQ >= cnt_q) continue;
            int cnt_k = qck[b];
            int nkt2 = (cnt_k + 63) >> 6;

            int qslot = qt * BQ + w * 16 + lq;
            bool qvalid = qslot < cnt_q;

            // Q fragment (single fp16), compacted row == qslot
            const u16* qbh = qh_g + ((size_t)b * LL + qslot) * DD + g * 8;
            half8 qhf[8];
#pragma unroll
            for (int ks = 0; ks < 8; ++ks)
                qhf[ks] = *(const half8*)(const void*)(qbh + ks * 32);

            float m = MASK_FILL, z = 0.f;
            f32x4 o[16];
#pragma unroll
            for (int i2 = 0; i2 < 16; ++i2) o[i2] = (f32x4){0.f, 0.f, 0.f, 0.f};

            const size_t kv_base = (size_t)b * LL * DD;
            const size_t vt_base = (size_t)b * DD * LL;

            if (nkt2 > 0) {
                int cur = 0;
                STAGE(0, 0);
                asm volatile("s_waitcnt vmcnt(0)" ::: "memory");
                __builtin_amdgcn_s_barrier();
                __builtin_amdgcn_sched_barrier(0);

                for (int kt2 = 0; kt2 < nkt2; ++kt2) {
                    int k0 = kt2 * 64;
                    if (kt2 + 1 < nkt2) STAGE(cur ^ 1, kt2 + 1);

                    // S^T = K @ Q^T over 64 keys (2 halves x 2 row-tiles)
                    f32x4 sa[2][2];
#pragma unroll
                    for (int hh = 0; hh < 2; ++hh)
#pragma unroll
                        for (int rt = 0; rt < 2; ++rt)
                            sa[hh][rt] = (f32x4){0.f, 0.f, 0.f, 0.f};
                    __builtin_amdgcn_s_setprio(1);
#pragma unroll
                    for (int hh = 0; hh < 2; ++hh) {
#pragma unroll
                        for (int ks = 0; ks < 8; ++ks) {
                            int cidx = ((ks * 4 + g) ^ (lq & 7)) * 8;
                            half8 kh0 = *(const half8*)(const void*)&khs[cur][hh][lq * 256 + cidx];
                            half8 kh1 = *(const half8*)(const void*)&khs[cur][hh][(16 + lq) * 256 + cidx];
                            sa[hh][0] = __builtin_amdgcn_mfma_f32_16x16x32_f16(kh0, qhf[ks], sa[hh][0], 0, 0, 0);
                            sa[hh][1] = __builtin_amdgcn_mfma_f32_16x16x32_f16(kh1, qhf[ks], sa[hh][1], 0, 0, 0);
                        }
                    }
                    __builtin_amdgcn_s_setprio(0);

                    float s[16];
#pragma unroll
                    for (int hh = 0; hh < 2; ++hh)
#pragma unroll
                        for (int i2 = 0; i2 < 4; ++i2) {
                            s[hh * 8 + i2]     = sa[hh][0][i2];
                            s[hh * 8 + 4 + i2] = sa[hh][1][i2];
                        }
                    if (kt2 == nkt2 - 1) {           // tail clamp: fake keys -> -inf
#pragma unroll
                        for (int hh = 0; hh < 2; ++hh) {
                            int base = k0 + hh * HB + 4 * g;
#pragma unroll
                            for (int i2 = 0; i2 < 4; ++i2) {
                                if (base + i2 >= cnt_k)      s[hh * 8 + i2]     = -1e30f;
                                if (base + 16 + i2 >= cnt_k) s[hh * 8 + 4 + i2] = -1e30f;
                            }
                        }
                    }
                    float pmax = s[0];
#pragma unroll
                    for (int i2 = 1; i2 < 16; ++i2) pmax = fmaxf(pmax, s[i2]);
                    pmax = fmaxf(pmax, __shfl_xor(pmax, 16));
                    pmax = fmaxf(pmax, __shfl_xor(pmax, 32));
                    if (__any(pmax > m)) {
                        float mnew = fmaxf(m, pmax);
                        float alpha = __expf(m - mnew);
                        z *= alpha;
#pragma unroll
                        for (int i2 = 0; i2 < 16; ++i2) o[i2] *= alpha;
                        m = mnew;
                    }
                    float p[16], psum = 0.f;
#pragma unroll
                    for (int i2 = 0; i2 < 16; ++i2) { p[i2] = __expf(s[i2] - m); psum += p[i2]; }
                    psum += __shfl_xor(psum, 16);
                    psum += __shfl_xor(psum, 32);
                    z += psum;

                    // P -> PV B-fragments (one per half), in-register exchange
                    union { unsigned u[4]; half8 v; } pf[2];
                    int srcA = ((lane & 16) << 1) | lq;
                    int srcB = srcA + 16;
                    bool sel = (g >> 1) != 0;
#pragma unroll
                    for (int hh = 0; hh < 2; ++hh) {
                        unsigned pk00 = pkf16(p[hh * 8 + 0], p[hh * 8 + 1]);
                        unsigned pk01 = pkf16(p[hh * 8 + 2], p[hh * 8 + 3]);
                        unsigned pk10 = pkf16(p[hh * 8 + 4], p[hh * 8 + 5]);
                        unsigned pk11 = pkf16(p[hh * 8 + 6], p[hh * 8 + 7]);
                        unsigned a00 = (unsigned)__shfl((int)pk00, srcA);
                        unsigned a01 = (unsigned)__shfl((int)pk01, srcA);
                        unsigned a10 = (unsigned)__shfl((int)pk10, srcA);
                        unsigned a11 = (unsigned)__shfl((int)pk11, srcA);
                        unsigned b00 = (unsigned)__shfl((int)pk00, srcB);
                        unsigned b01 = (unsigned)__shfl((int)pk01, srcB);
                        unsigned b10 = (unsigned)__shfl((int)pk10, srcB);
                        unsigned b11 = (unsigned)__shfl((int)pk11, srcB);
                        pf[hh].u[0] = sel ? a10 : a00;
                        pf[hh].u[1] = sel ? a11 : a01;
                        pf[hh].u[2] = sel ? b10 : b00;
                        pf[hh].u[3] = sel ? b11 : b01;
                    }

                    // O^T += V^T @ P^T (both halves)
                    __builtin_amdgcn_s_setprio(1);
#pragma unroll
                    for (int dt = 0; dt < 16; ++dt) {
                        int d = dt * 16 + lq;
                        half8 vf0 = *(const half8*)(const void*)&vts[cur][0][d * 32 + pvcc];
                        half8 vf1 = *(const half8*)(const void*)&vts[cur][1][d * 32 + pvcc];
                        o[dt] = __builtin_amdgcn_mfma_f32_16x16x32_f16(vf0, pf[0].v, o[dt], 0, 0, 0);
                        o[dt] = __builtin_amdgcn_mfma_f32_16x16x32_f16(vf1, pf[1].v, o[dt], 0, 0, 0);
                    }
                    __builtin_amdgcn_s_setprio(0);

                    if (kt2 + 1 < nkt2) {
                        asm volatile("s_waitcnt vmcnt(0)" ::: "memory");
                        __builtin_amdgcn_s_barrier();
                        __builtin_amdgcn_sched_barrier(0);
                    }
                    cur ^= 1;
                }
            }

            // exact masked-key lump: all masked logits == MASK_FILL
            float wl = __expf(MASK_FILL - m);      // m >= MASK_FILL always
            z += (float)(LL - cnt_k) * wl;
#pragma unroll
            for (int dt = 0; dt < 16; ++dt) {
                f32x4 vv = *(const f32x4*)(vsp + dt * 16 + 4 * g);
                o[dt] += wl * vv;
            }

            if (qvalid) {
                int qrow = qidx[b * LL + qslot];
                float zinv = 1.0f / z;
                float* orow = ob + ((size_t)b * LL + qrow) * DD + 4 * g;
#pragma unroll
                for (int dt = 0; dt < 16; ++dt) {
                    f32x4 vv = o[dt] * zinv;
                    *(f32x4*)(orow + dt * 16) = vv;
                }
            }
        }
    }
#undef STAGE
}

extern "C" void kernel_launch(void* const* d_in, const int* in_sizes, int n_in,
                              void* d_out, int out_size, void* d_ws, size_t ws_size,
                              hipStream_t stream)
{
    const float* v1      = (const float*)d_in[0];
    const void*  v1_mask = d_in[1];
    const float* v2      = (const float*)d_in[2];
    const void*  v2_mask = d_in[3];
    float* out = (float*)d_out;

    u16* v1h = (u16*)d_ws;           // compacted fp16 (row = compact slot)
    u16* v2h = v1h + ELEMS;
    u16* v1t = v2h + ELEMS;          // compacted fp16 transpose [b][d][slot]
    u16* v2t = v1t + ELEMS;
    int* qidx1 = (int*)(v2t + ELEMS);
    int* qcnt1 = qidx1 + NB * LL;
    int* qidx2 = qcnt1 + NB;
    int* qcnt2 = qidx2 + NB * LL;
    int* cm1   = qcnt2 + NB;
    int* cm2   = cm1 + NB * LL;
    int* pa1   = cm2 + NB * LL;
    int* pa2   = pa1 + NB * LL;
    int* ctr   = pa2 + NB * LL;                  // [8] steal counters
    float* part = (float*)(ctr + 16);            // [2][NB][16][256]
    float* vsum = part + 2 * NB * 16 * 256;      // [2][NB][256]

    prep_masks<<<dim3(128), dim3(256), 0, stream>>>(
        v1_mask, v2_mask, cm1, cm2,
        qidx1, pa1, qcnt1, qidx2, pa2, qcnt2, ctr);

    prep2_kernel<<<dim3(2 * NB * 64), dim3(256), 0, stream>>>(
        v1, v1h, v1t, cm1, pa1, qidx1, qcnt1,
        v2, v2h, v2t, cm2, pa2, qidx2, qcnt2, part, out);
    vsum_reduce<<<dim3(2 * NB), dim3(256), 0, stream>>>(part, vsum);

    // persistent, work-stealing fused flash (1 block/CU, 128KB LDS)
    flash_fused<<<dim3(256), dim3(512), 0, stream>>>(
        v1h, v2h, v1t, v2t,
        qidx1, qcnt1, qidx2, qcnt2, vsum, ctr, out);
}

// Round 12
// 208.559 us; speedup vs baseline: 2.5450x; 1.0216x over previous
//
#include <hip/hip_runtime.h>
#include <hip/hip_bf16.h>
#include <hip/hip_fp16.h>
#include <stdint.h>

// BidirectionalAttention2: two flash-attention passes over sim = v1 @ v2^T.
// R12: (1) prep2 transpose writes vectorized (u16x4 slot-aligned quads; was
//      16 scalar u16 stores/thread ~27us of store issue). (2) flash: PV V^T
//      fragments for dt=0..7 preloaded between QK and softmax (+64 VGPR, free:
//      1-block/8-wave residency is VGPR-insensitive up to 256) so their LDS
//      latency hides under the softmax VALU phase. Kept from R11: fp16
//      single-pass QK, BK=64 double-buffer, exact masked-key lump, compacted
//      K/V, per-XCD work steal, setprio.

#define MASK_FILL -1e-07f

typedef unsigned short u16;
typedef _Float16 half8 __attribute__((ext_vector_type(8)));
typedef __attribute__((ext_vector_type(4))) float f32x4;
typedef __attribute__((ext_vector_type(4))) u16 u16x4;

#define NB 64
#define LL 1024
#define DD 256
#define BQ 128
#define HB 32                 // half-block of keys (sub-tile)
#define ELEMS ((size_t)NB * LL * DD)
#define NIT_STREAM 128        // items per stream: qt(8) x dir(2) x boct(8)

__device__ __forceinline__ u16 f16b(float f) {
    _Float16 h = (_Float16)f;
    return __builtin_bit_cast(u16, h);
}
__device__ __forceinline__ unsigned pkf16(float a, float b) {
    return (unsigned)f16b(a) | ((unsigned)f16b(b) << 16);
}

__device__ __forceinline__ void gll16(const u16* g, u16* l) {
    __builtin_amdgcn_global_load_lds(
        (const __attribute__((address_space(1))) void*)g,
        (__attribute__((address_space(3))) void*)l, 16, 0, 0);
}

// ---- fused: mask dtype detect + convert + per-batch compaction + ctr clear --
__global__ __launch_bounds__(256) void prep_masks(
    const void* __restrict__ m1, const void* __restrict__ m2,
    int* __restrict__ cm1, int* __restrict__ cm2,
    int* __restrict__ qidx1, int* __restrict__ pa1, int* __restrict__ qcnt1,
    int* __restrict__ qidx2, int* __restrict__ pa2, int* __restrict__ qcnt2,
    int* __restrict__ ctr)
{
    int blk = blockIdx.x, tid = threadIdx.x;
    int msk = blk >> 6, b = blk & 63;
    const unsigned* w1 = (const unsigned*)m1;
    const unsigned* w2 = (const unsigned*)m2;
    unsigned acc = 0;
    for (int i = tid; i < 4096; i += 256) acc |= (w1[i] | w2[i]) & ~1u;
    __shared__ unsigned red[256];
    red[tid] = acc;
    __syncthreads();
    for (int o = 128; o; o >>= 1) {
        if (tid < o) red[tid] |= red[tid + o];
        __syncthreads();
    }
    int isbool = red[0] ? 1 : 0;

    const void* m = msk ? m2 : m1;
    int* cm   = msk ? cm2 : cm1;
    int* qidx = msk ? qidx2 : qidx1;
    int* pa   = msk ? pa2 : pa1;
    int* qcnt = msk ? qcnt2 : qcnt1;

    __shared__ int ps[256];
    int f[4], s = 0;
#pragma unroll
    for (int j = 0; j < 4; ++j) {
        int idx = b * LL + tid * 4 + j;
        int v = isbool ? (int)((const unsigned char*)m)[idx] : ((const int*)m)[idx];
        cm[idx] = v ? 1 : 0;
        f[j] = (v == 0) ? 1 : 0;
        s += f[j];
    }
    ps[tid] = s;
    __syncthreads();
    for (int off = 1; off < 256; off <<= 1) {
        int v = (tid >= off) ? ps[tid - off] : 0;
        __syncthreads();
        ps[tid] += v;
        __syncthreads();
    }
    int pos = (tid > 0) ? ps[tid - 1] : 0;
#pragma unroll
    for (int j = 0; j < 4; ++j) {
        pa[b * LL + tid * 4 + j] = pos;
        if (f[j]) qidx[b * LL + (pos++)] = tid * 4 + j;
    }
    if (tid == 255) qcnt[b] = ps[255];
    if (blk == 0 && tid < 8) ctr[tid] = 0;
}

// ---- prep: fp32 -> fp16 COMPACTED rows + compacted fp16 transpose +
// ---- masked-V partial sums + zeroing of masked output rows (fused) ----------
__global__ __launch_bounds__(256) void prep2_kernel(
    const float* __restrict__ x1, u16* __restrict__ h1, u16* __restrict__ t1,
    const int* __restrict__ cm1, const int* __restrict__ pa1,
    const int* __restrict__ qi1, const int* __restrict__ qc1,
    const float* __restrict__ x2, u16* __restrict__ h2, u16* __restrict__ t2,
    const int* __restrict__ cm2, const int* __restrict__ pa2,
    const int* __restrict__ qi2, const int* __restrict__ qc2,
    float* __restrict__ part, float* __restrict__ out)
{
    __shared__ u16 t[64][65];
    __shared__ float ps2[16][68];
    int blk = blockIdx.x;
    int tensor = blk >> 12;
    blk &= 4095;
    const float* x = tensor ? x2 : x1;
    u16* h  = tensor ? h2 : h1;
    u16* xt = tensor ? t2 : t1;
    const int* cm = tensor ? cm2 : cm1;
    const int* pa = tensor ? pa2 : pa1;
    const int* qi = tensor ? qi2 : qi1;
    const int* qc = tensor ? qc2 : qc1;
    float* outb = out + (tensor ? ELEMS : 0);
    int b = blk >> 6, lt = (blk >> 2) & 15, dt = blk & 3;
    int l0 = lt * 64, d0 = dt * 64;
    int tid = threadIdx.x;
    int sub = tid >> 4;
    int c16 = tid & 15;
    float vpart[4] = {0.f, 0.f, 0.f, 0.f};
#pragma unroll
    for (int p = 0; p < 4; ++p) {
        int row = p * 16 + sub;
        int l = l0 + row;
        int masked = cm[b * LL + l];
        int slot = pa[b * LL + l];
        f32x4 v = *(const f32x4*)(x + ((size_t)b * LL + l) * DD + d0 + c16 * 4);
        u16x4 hv;
#pragma unroll
        for (int e = 0; e < 4; ++e) {
            hv[e] = f16b(v[e]);
            t[c16 * 4 + e][row] = hv[e];
            if (masked) vpart[e] += v[e];
        }
        if (!masked) {
            *(u16x4*)(h + ((size_t)b * LL + slot) * DD + d0 + c16 * 4) = hv;
        } else {
            f32x4 z4 = {0.f, 0.f, 0.f, 0.f};
            *(f32x4*)(outb + ((size_t)b * LL + l) * DD + d0 + c16 * 4) = z4;
        }
    }
#pragma unroll
    for (int e = 0; e < 4; ++e) ps2[sub][c16 * 4 + e] = vpart[e];
    __syncthreads();
    // compacted transpose, slot-aligned u16x4 stores (head/tail scalar)
    int first = pa[b * LL + l0];
    int cntb = qc[b];
    int nun = ((lt == 15) ? cntb : pa[b * LL + l0 + 64]) - first;
    int last = first + nun;
    int q0 = first >> 2;
    int nq = ((last + 3) >> 2) - q0;     // <= 17 aligned quads
    const int* qib = qi + b * LL;
#pragma unroll
    for (int p = 0; p < 4; ++p) {
        int d = p * 16 + sub;
        u16* xrow = xt + ((size_t)b * DD + d0 + d) * LL;
        for (int qq = c16; qq < nq; qq += 16) {
            int s0 = (q0 + qq) << 2;
            if (s0 >= first && s0 + 4 <= last) {
                u16x4 ov;
#pragma unroll
                for (int e = 0; e < 4; ++e) {
                    int col = qib[s0 + e] - l0;
                    ov[e] = t[d][col];
                }
                *(u16x4*)(xrow + s0) = ov;
            } else {
#pragma unroll
                for (int e = 0; e < 4; ++e) {
                    int sl = s0 + e;
                    if (sl >= first && sl < last) {
                        int col = qib[sl] - l0;
                        xrow[sl] = t[d][col];
                    }
                }
            }
        }
    }
    if (tid < 64) {
        float s = 0.f;
#pragma unroll
        for (int k = 0; k < 16; ++k) s += ps2[k][tid];
        part[(((size_t)tensor * NB + b) * 16 + lt) * 256 + d0 + tid] = s;
    }
}

// ---- reduce per-tile partials -> Vsum[tensor][b][256] (fixed order) ---------
__global__ __launch_bounds__(256) void vsum_reduce(
    const float* __restrict__ part, float* __restrict__ vsum)
{
    int blk = blockIdx.x;       // tensor*NB + b
    int d = threadIdx.x;
    float s = 0.f;
#pragma unroll
    for (int lt = 0; lt < 16; ++lt)
        s += part[((size_t)blk * 16 + lt) * 256 + d];
    vsum[(size_t)blk * DD + d] = s;
}

// ---- persistent fused flash: fp16 1-pass QK, 64 keys/barrier, 128KB LDS -----
// 256 blocks x 512 thr (1/CU). stream = blockIdx&7 -> batches b%8.
__global__ __launch_bounds__(512, 2) void flash_fused(
    const u16* __restrict__ v1h, const u16* __restrict__ v2h,
    const u16* __restrict__ v1t, const u16* __restrict__ v2t,
    const int* __restrict__ qidx1, const int* __restrict__ qcnt1,
    const int* __restrict__ qidx2, const int* __restrict__ qcnt2,
    const float* __restrict__ vsum, int* __restrict__ ctr,
    float* __restrict__ out)
{
    int strm0 = blockIdx.x & 7;
    int tid = threadIdx.x;
    int w = tid >> 6, lane = tid & 63;
    int lq = lane & 15, g = lane >> 4;

    __shared__ __align__(16) u16 khs[2][2][HB * DD];  // [key][d], chunk ^ (key&7)
    __shared__ __align__(16) u16 vts[2][2][HB * DD];  // [d][key], chunk ^ (d&3)^((d>>2)&3)

    const int pvcc = (g ^ (lq & 3) ^ ((lq >> 2) & 3)) * 8;

#define STAGE(BUF, KT2)                                                         \
    {                                                                           \
        int k0s = (KT2) * 64;                                                   \
        _Pragma("unroll")                                                       \
        for (int t = 0; t < 8; ++t) {                                           \
            int u = t * 8 + w;                                                  \
            int n = u & 15;                                                     \
            int hh = (u >> 4) & 1;                                              \
            if (u < 32) {                                                       \
                unsigned phys = (unsigned)n * 1024u + (unsigned)lane * 16u;     \
                unsigned key = phys >> 9;                                       \
                unsigned cl = ((phys >> 4) & 31u) ^ (key & 7u);                 \
                size_t koff = kv_base + (size_t)(k0s + hh * HB + (int)key) * DD + cl * 8; \
                gll16(kh_g + koff, &khs[BUF][hh][n * 512]);                     \
            } else {                                                            \
                unsigned dv = (unsigned)n * 16u + ((unsigned)lane >> 2);        \
                unsigned cv = ((unsigned)lane & 3u) ^ (dv & 3u) ^ ((dv >> 2) & 3u); \
                size_t voff = vt_base + (size_t)dv * LL + (unsigned)(k0s + hh * HB) + cv * 8; \
                gll16(vt_g + voff, &vts[BUF][hh][n * 512]);                     \
            }                                                                   \
        }                                                                       \
    }

    for (int ss = 0; ss < 8; ++ss) {
        int s2 = (strm0 + ss) & 7;
        for (;;) {
            __syncthreads();                       // prev item's LDS reads done
            if (tid == 0) *(int*)&khs[0][0][0] = atomicAdd(&ctr[s2], 1);
            __syncthreads();
            int it = *(const int*)&khs[0][0][0];
            __syncthreads();                       // all read it before overwrite
            if (it >= NIT_STREAM) break;
            int qt  = it & 7;
            int dir = (it >> 3) & 1;
            int b   = ((it >> 4) << 3) + s2;

            const u16 *qh_g, *kh_g, *vt_g;
            const int *qidx, *qcq, *qck;
            const float* vsp;
            float* ob;
            if (dir == 0) { qh_g=v1h; kh_g=v2h; vt_g=v2t;
                            qidx=qidx1; qcq=qcnt1; qck=qcnt2;
                            vsp = vsum + ((size_t)NB + b) * DD; ob = out; }
            else          { qh_g=v2h; kh_g=v1h; vt_g=v1t;
                            qidx=qidx2; qcq=qcnt2; qck=qcnt1;
                            vsp = vsum + (size_t)b * DD; ob = out + ELEMS; }
            int cnt_q = qcq[b];
            if (qt * BQ >= cnt_q) continue;
            int cnt_k = qck[b];
            int nkt2 = (cnt_k + 63) >> 6;

            int qslot = qt * BQ + w * 16 + lq;
            bool qvalid = qslot < cnt_q;

            const u16* qbh = qh_g + ((size_t)b * LL + qslot) * DD + g * 8;
            half8 qhf[8];
#pragma unroll
            for (int ks = 0; ks < 8; ++ks)
                qhf[ks] = *(const half8*)(const void*)(qbh + ks * 32);

            float m = MASK_FILL, z = 0.f;
            f32x4 o[16];
#pragma unroll
            for (int i2 = 0; i2 < 16; ++i2) o[i2] = (f32x4){0.f, 0.f, 0.f, 0.f};

            const size_t kv_base = (size_t)b * LL * DD;
            const size_t vt_base = (size_t)b * DD * LL;

            if (nkt2 > 0) {
                int cur = 0;
                STAGE(0, 0);
                asm volatile("s_waitcnt vmcnt(0)" ::: "memory");
                __builtin_amdgcn_s_barrier();
                __builtin_amdgcn_sched_barrier(0);

                for (int kt2 = 0; kt2 < nkt2; ++kt2) {
                    int k0 = kt2 * 64;
                    if (kt2 + 1 < nkt2) STAGE(cur ^ 1, kt2 + 1);

                    // S^T = K @ Q^T over 64 keys (2 halves x 2 row-tiles)
                    f32x4 sa[2][2];
#pragma unroll
                    for (int hh = 0; hh < 2; ++hh)
#pragma unroll
                        for (int rt = 0; rt < 2; ++rt)
                            sa[hh][rt] = (f32x4){0.f, 0.f, 0.f, 0.f};
                    __builtin_amdgcn_s_setprio(1);
#pragma unroll
                    for (int hh = 0; hh < 2; ++hh) {
#pragma unroll
                        for (int ks = 0; ks < 8; ++ks) {
                            int cidx = ((ks * 4 + g) ^ (lq & 7)) * 8;
                            half8 kh0 = *(const half8*)(const void*)&khs[cur][hh][lq * 256 + cidx];
                            half8 kh1 = *(const half8*)(const void*)&khs[cur][hh][(16 + lq) * 256 + cidx];
                            sa[hh][0] = __builtin_amdgcn_mfma_f32_16x16x32_f16(kh0, qhf[ks], sa[hh][0], 0, 0, 0);
                            sa[hh][1] = __builtin_amdgcn_mfma_f32_16x16x32_f16(kh1, qhf[ks], sa[hh][1], 0, 0, 0);
                        }
                    }
                    __builtin_amdgcn_s_setprio(0);

                    // preload PV A-fragments for dt=0..7: their LDS latency
                    // hides under the softmax VALU phase below (+64 VGPR, free)
                    half8 vfA[8], vfB[8];
#pragma unroll
                    for (int dt = 0; dt < 8; ++dt) {
                        int d = dt * 16 + lq;
                        vfA[dt] = *(const half8*)(const void*)&vts[cur][0][d * 32 + pvcc];
                        vfB[dt] = *(const half8*)(const void*)&vts[cur][1][d * 32 + pvcc];
                    }

                    float s[16];
#pragma unroll
                    for (int hh = 0; hh < 2; ++hh)
#pragma unroll
                        for (int i2 = 0; i2 < 4; ++i2) {
                            s[hh * 8 + i2]     = sa[hh][0][i2];
                            s[hh * 8 + 4 + i2] = sa[hh][1][i2];
                        }
                    if (kt2 == nkt2 - 1) {           // tail clamp: fake keys -> -inf
#pragma unroll
                        for (int hh = 0; hh < 2; ++hh) {
                            int base = k0 + hh * HB + 4 * g;
#pragma unroll
                            for (int i2 = 0; i2 < 4; ++i2) {
                                if (base + i2 >= cnt_k)      s[hh * 8 + i2]     = -1e30f;
                                if (base + 16 + i2 >= cnt_k) s[hh * 8 + 4 + i2] = -1e30f;
                            }
                        }
                    }
                    float pmax = s[0];
#pragma unroll
                    for (int i2 = 1; i2 < 16; ++i2) pmax = fmaxf(pmax, s[i2]);
                    pmax = fmaxf(pmax, __shfl_xor(pmax, 16));
                    pmax = fmaxf(pmax, __shfl_xor(pmax, 32));
                    if (__any(pmax > m)) {
                        float mnew = fmaxf(m, pmax);
                        float alpha = __expf(m - mnew);
                        z *= alpha;
#pragma unroll
                        for (int i2 = 0; i2 < 16; ++i2) o[i2] *= alpha;
                        m = mnew;
                    }
                    float p[16], psum = 0.f;
#pragma unroll
                    for (int i2 = 0; i2 < 16; ++i2) { p[i2] = __expf(s[i2] - m); psum += p[i2]; }
                    psum += __shfl_xor(psum, 16);
                    psum += __shfl_xor(psum, 32);
                    z += psum;

                    // P -> PV B-fragments (one per half), in-register exchange
                    union { unsigned u[4]; half8 v; } pf[2];
                    int srcA = ((lane & 16) << 1) | lq;
                    int srcB = srcA + 16;
                    bool sel = (g >> 1) != 0;
#pragma unroll
                    for (int hh = 0; hh < 2; ++hh) {
                        unsigned pk00 = pkf16(p[hh * 8 + 0], p[hh * 8 + 1]);
                        unsigned pk01 = pkf16(p[hh * 8 + 2], p[hh * 8 + 3]);
                        unsigned pk10 = pkf16(p[hh * 8 + 4], p[hh * 8 + 5]);
                        unsigned pk11 = pkf16(p[hh * 8 + 6], p[hh * 8 + 7]);
                        unsigned a00 = (unsigned)__shfl((int)pk00, srcA);
                        unsigned a01 = (unsigned)__shfl((int)pk01, srcA);
                        unsigned a10 = (unsigned)__shfl((int)pk10, srcA);
                        unsigned a11 = (unsigned)__shfl((int)pk11, srcA);
                        unsigned b00 = (unsigned)__shfl((int)pk00, srcB);
                        unsigned b01 = (unsigned)__shfl((int)pk01, srcB);
                        unsigned b10 = (unsigned)__shfl((int)pk10, srcB);
                        unsigned b11 = (unsigned)__shfl((int)pk11, srcB);
                        pf[hh].u[0] = sel ? a10 : a00;
                        pf[hh].u[1] = sel ? a11 : a01;
                        pf[hh].u[2] = sel ? b10 : b00;
                        pf[hh].u[3] = sel ? b11 : b01;
                    }

                    // O^T += V^T @ P^T: dt 0..7 from preloaded regs, 8..15 inline
                    __builtin_amdgcn_s_setprio(1);
#pragma unroll
                    for (int dt = 0; dt < 8; ++dt) {
                        o[dt] = __builtin_amdgcn_mfma_f32_16x16x32_f16(vfA[dt], pf[0].v, o[dt], 0, 0, 0);
                        o[dt] = __builtin_amdgcn_mfma_f32_16x16x32_f16(vfB[dt], pf[1].v, o[dt], 0, 0, 0);
                    }
#pragma unroll
                    for (int dt = 8; dt < 16; ++dt) {
                        int d = dt * 16 + lq;
                        half8 vf0 = *(const half8*)(const void*)&vts[cur][0][d * 32 + pvcc];
                        half8 vf1 = *(const half8*)(const void*)&vts[cur][1][d * 32 + pvcc];
                        o[dt] = __builtin_amdgcn_mfma_f32_16x16x32_f16(vf0, pf[0].v, o[dt], 0, 0, 0);
                        o[dt] = __builtin_amdgcn_mfma_f32_16x16x32_f16(vf1, pf[1].v, o[dt], 0, 0, 0);
                    }
                    __builtin_amdgcn_s_setprio(0);

                    if (kt2 + 1 < nkt2) {
                        asm volatile("s_waitcnt vmcnt(0)" ::: "memory");
                        __builtin_amdgcn_s_barrier();
                        __builtin_amdgcn_sched_barrier(0);
                    }
                    cur ^= 1;
                }
            }

            // exact masked-key lump: all masked logits == MASK_FILL
            float wl = __expf(MASK_FILL - m);      // m >= MASK_FILL always
            z += (float)(LL - cnt_k) * wl;
#pragma unroll
            for (int dt = 0; dt < 16; ++dt) {
                f32x4 vv = *(const f32x4*)(vsp + dt * 16 + 4 * g);
                o[dt] += wl * vv;
            }

            if (qvalid) {
                int qrow = qidx[b * LL + qslot];
                float zinv = 1.0f / z;
                float* orow = ob + ((size_t)b * LL + qrow) * DD + 4 * g;
#pragma unroll
                for (int dt = 0; dt < 16; ++dt) {
                    f32x4 vv = o[dt] * zinv;
                    *(f32x4*)(orow + dt * 16) = vv;
                }
            }
        }
    }
#undef STAGE
}

extern "C" void kernel_launch(void* const* d_in, const int* in_sizes, int n_in,
                              void* d_out, int out_size, void* d_ws, size_t ws_size,
                              hipStream_t stream)
{
    const float* v1      = (const float*)d_in[0];
    const void*  v1_mask = d_in[1];
    const float* v2      = (const float*)d_in[2];
    const void*  v2_mask = d_in[3];
    float* out = (float*)d_out;

    u16* v1h = (u16*)d_ws;           // compacted fp16 (row = compact slot)
    u16* v2h = v1h + ELEMS;
    u16* v1t = v2h + ELEMS;          // compacted fp16 transpose [b][d][slot]
    u16* v2t = v1t + ELEMS;
    int* qidx1 = (int*)(v2t + ELEMS);
    int* qcnt1 = qidx1 + NB * LL;
    int* qidx2 = qcnt1 + NB;
    int* qcnt2 = qidx2 + NB * LL;
    int* cm1   = qcnt2 + NB;
    int* cm2   = cm1 + NB * LL;
    int* pa1   = cm2 + NB * LL;
    int* pa2   = pa1 + NB * LL;
    int* ctr   = pa2 + NB * LL;                  // [8] steal counters
    float* part = (float*)(ctr + 16);            // [2][NB][16][256]
    float* vsum = part + 2 * NB * 16 * 256;      // [2][NB][256]

    prep_masks<<<dim3(128), dim3(256), 0, stream>>>(
        v1_mask, v2_mask, cm1, cm2,
        qidx1, pa1, qcnt1, qidx2, pa2, qcnt2, ctr);

    prep2_kernel<<<dim3(2 * NB * 64), dim3(256), 0, stream>>>(
        v1, v1h, v1t, cm1, pa1, qidx1, qcnt1,
        v2, v2h, v2t, cm2, pa2, qidx2, qcnt2, part, out);
    vsum_reduce<<<dim3(2 * NB), dim3(256), 0, stream>>>(part, vsum);

    // persistent, work-stealing fused flash (1 block/CU, 128KB LDS)
    flash_fused<<<dim3(256), dim3(512), 0, stream>>>(
        v1h, v2h, v1t, v2t,
        qidx1, qcnt1, qidx2, qcnt2, vsum, ctr, out);
}